// Round 1
// baseline (761.838 us; speedup 1.0000x reference)
//
#include <hip/hip_runtime.h>
#include <math.h>

#define BB   2
#define SS   1024
#define HH   768
#define DD   24
#define HIDD 96
#define VINN 2304   // 3*H
#define VHIDD 768

// ---------------- Kernel 1: projections Zj,Zi (H->D) and tj,ti (D->HID) ----
__global__ __launch_bounds__(256) void k_proj(
    const float* __restrict__ Hj, const float* __restrict__ Hi,
    const float* __restrict__ Wpj, const float* __restrict__ Wpi,
    const float* __restrict__ W1,
    float* __restrict__ Zj, float* __restrict__ Zi,
    float* __restrict__ Tj, float* __restrict__ Ti)
{
    int row = blockIdx.x;           // b*S + s
    int tid = threadIdx.x;
    __shared__ float sHj[HH], sHi[HH], sZ[2*DD];
    for (int k = tid; k < HH; k += 256) {
        sHj[k] = Hj[(size_t)row*HH + k];
        sHi[k] = Hi[(size_t)row*HH + k];
    }
    __syncthreads();
    int wave = tid >> 6, lane = tid & 63;
    for (int o = wave; o < 2*DD; o += 4) {
        int d = (o < DD) ? o : o - DD;
        const float* hrow = (o < DD) ? sHj : sHi;
        const float* wp   = (o < DD) ? Wpj : Wpi;
        float acc = 0.f;
        for (int k = lane; k < HH; k += 64)
            acc = fmaf(hrow[k], wp[k*DD + d], acc);
        #pragma unroll
        for (int off = 32; off; off >>= 1) acc += __shfl_down(acc, off, 64);
        if (lane == 0) sZ[o] = acc;
    }
    __syncthreads();
    if (tid < 2*DD) {
        float z = sZ[tid];
        if (tid < DD) Zj[(size_t)row*DD + tid]      = z;
        else          Zi[(size_t)row*DD + tid - DD] = z;
    }
    if (tid < 2*HIDD) {
        int h = tid % HIDD, which = tid / HIDD;   // 0 -> tj (W1a), 1 -> ti (W1b)
        const float* zz = which ? (sZ + DD) : sZ;
        const float* w  = W1 + (which ? DD*HIDD : 0);
        float acc = 0.f;
        #pragma unroll
        for (int d = 0; d < DD; ++d) acc = fmaf(zz[d], w[d*HIDD + h], acc);
        if (which == 0) Tj[(size_t)row*HIDD + h] = acc;
        else            Ti[(size_t)row*HIDD + h] = acc;
    }
}

// ---------------- Kernel 2: logits + softmax -> probs ----------------------
// One block per (b,s). Each thread owns 4 t-values (2 reps x 2-way blocking).
__global__ __launch_bounds__(256) void k_attn(
    const float* __restrict__ Zj, const float* __restrict__ Zi,
    const float* __restrict__ Tj, const float* __restrict__ Ti,
    const float* __restrict__ W1, const float* __restrict__ b1,
    const float* __restrict__ W2, const float* __restrict__ b2,
    const float* __restrict__ mask, float* __restrict__ probs)
{
    int row = blockIdx.x;       // b*S + s
    int b = row >> 10;
    int tid = threadIdx.x;
    __shared__ float sWc[DD][HIDD], sWd[DD][HIDD];
    __shared__ float sW2[HIDD], sBase[HIDD], sZj[DD];
    __shared__ float sLog[SS];
    __shared__ float sRed[4];

    for (int i = tid; i < DD*HIDD; i += 256) {
        (&sWc[0][0])[i] = W1[2*DD*HIDD + i];   // W1c rows 48..71
        (&sWd[0][0])[i] = W1[3*DD*HIDD + i];   // W1d rows 72..95
    }
    if (tid < HIDD) {
        sW2[tid]   = W2[tid];
        sBase[tid] = Tj[(size_t)row*HIDD + tid] + b1[tid];
    }
    if (tid < DD) sZj[tid] = Zj[(size_t)row*DD + tid];
    float b2v = b2[0];
    __syncthreads();

    for (int rep = 0; rep < 2; ++rep) {
        int t0 = tid + rep*512;
        int t1 = t0 + 256;
        const float* zi0 = Zi + ((size_t)(b<<10) + t0)*DD;
        const float* zi1 = Zi + ((size_t)(b<<10) + t1)*DD;
        float p0[DD], q0[DD], p1[DD], q1[DD];
        #pragma unroll
        for (int d = 0; d < DD; ++d) {
            float zj = sZj[d];
            float a0 = zi0[d], a1 = zi1[d];
            p0[d] = zj*a0; q0[d] = fabsf(zj - a0);
            p1[d] = zj*a1; q1[d] = fabsf(zj - a1);
        }
        const float* ti0 = Ti + ((size_t)(b<<10) + t0)*HIDD;
        const float* ti1 = Ti + ((size_t)(b<<10) + t1)*HIDD;
        float l0 = 0.f, l1 = 0.f;
        for (int hg = 0; hg < HIDD; hg += 4) {
            float4 u0 = *(const float4*)(ti0 + hg);
            float4 u1 = *(const float4*)(ti1 + hg);
            float4 bs = *(const float4*)(sBase + hg);
            float v0[4] = {u0.x+bs.x, u0.y+bs.y, u0.z+bs.z, u0.w+bs.w};
            float v1[4] = {u1.x+bs.x, u1.y+bs.y, u1.z+bs.z, u1.w+bs.w};
            #pragma unroll
            for (int d = 0; d < DD; ++d) {
                float4 wc = *(const float4*)(&sWc[d][hg]);
                float4 wd = *(const float4*)(&sWd[d][hg]);
                float wcv[4] = {wc.x, wc.y, wc.z, wc.w};
                float wdv[4] = {wd.x, wd.y, wd.z, wd.w};
                #pragma unroll
                for (int j = 0; j < 4; ++j) {
                    v0[j] = fmaf(p0[d], wcv[j], v0[j]);
                    v0[j] = fmaf(q0[d], wdv[j], v0[j]);
                    v1[j] = fmaf(p1[d], wcv[j], v1[j]);
                    v1[j] = fmaf(q1[d], wdv[j], v1[j]);
                }
            }
            float4 w2 = *(const float4*)(sW2 + hg);
            float w2v[4] = {w2.x, w2.y, w2.z, w2.w};
            #pragma unroll
            for (int j = 0; j < 4; ++j) {
                l0 += fmaxf(v0[j], 0.f) * w2v[j];
                l1 += fmaxf(v1[j], 0.f) * w2v[j];
            }
        }
        l0 += b2v; l1 += b2v;
        l0 += (1.0f - mask[(size_t)(b<<10) + t0]) * (-3.402823466e+38f);
        l1 += (1.0f - mask[(size_t)(b<<10) + t1]) * (-3.402823466e+38f);
        sLog[t0] = l0;
        sLog[t1] = l1;
    }
    __syncthreads();

    // softmax over t (S=1024) within the block
    int lane = tid & 63, wave = tid >> 6;
    float m = -3.402823466e+38f;
    #pragma unroll
    for (int i = 0; i < 4; ++i) m = fmaxf(m, sLog[tid + i*256]);
    #pragma unroll
    for (int off = 32; off; off >>= 1) m = fmaxf(m, __shfl_down(m, off, 64));
    if (lane == 0) sRed[wave] = m;
    __syncthreads();
    float M = fmaxf(fmaxf(sRed[0], sRed[1]), fmaxf(sRed[2], sRed[3]));
    float e[4]; float ssum = 0.f;
    #pragma unroll
    for (int i = 0; i < 4; ++i) { e[i] = expf(sLog[tid + i*256] - M); ssum += e[i]; }
    #pragma unroll
    for (int off = 32; off; off >>= 1) ssum += __shfl_down(ssum, off, 64);
    __syncthreads();               // all reads of sRed (for M) complete
    if (lane == 0) sRed[wave] = ssum;
    __syncthreads();
    float inv = 1.0f / (sRed[0]+sRed[1]+sRed[2]+sRed[3]);
    #pragma unroll
    for (int i = 0; i < 4; ++i)
        probs[(size_t)row*SS + tid + i*256] = e[i] * inv;
}

// ---------------- Kernel 3: ctx = probs @ H_i, epilogue builds msg_in ------
__global__ __launch_bounds__(256) void k_ctx(
    const float* __restrict__ probs, const float* __restrict__ Hi,
    const float* __restrict__ Hj, float* __restrict__ msgin)
{
    int b = blockIdx.z;
    const float* A  = probs + (size_t)b*SS*SS;
    const float* Bm = Hi    + (size_t)b*SS*HH;
    __shared__ float sA[64][20];
    __shared__ float sB[16][64];
    int tid = threadIdx.x;
    int tx = tid & 15, ty = tid >> 4;
    int r0 = blockIdx.y * 64, c0 = blockIdx.x * 64;
    float acc[4][4] = {};
    for (int kb = 0; kb < SS; kb += 16) {
        int idx = tid * 4;
        int ra = idx >> 4, ka = idx & 15;
        *(float4*)&sA[ra][ka] = *(const float4*)(A + (size_t)(r0+ra)*SS + kb + ka);
        int kbb = idx >> 6, cb = idx & 63;
        *(float4*)&sB[kbb][cb] = *(const float4*)(Bm + (size_t)(kb+kbb)*HH + c0 + cb);
        __syncthreads();
        #pragma unroll
        for (int kk = 0; kk < 16; ++kk) {
            float a[4];
            #pragma unroll
            for (int i = 0; i < 4; ++i) a[i] = sA[ty*4+i][kk];
            float4 bv = *(const float4*)&sB[kk][tx*4];
            float bbv[4] = {bv.x, bv.y, bv.z, bv.w};
            #pragma unroll
            for (int i = 0; i < 4; ++i)
                #pragma unroll
                for (int j = 0; j < 4; ++j)
                    acc[i][j] = fmaf(a[i], bbv[j], acc[i][j]);
        }
        __syncthreads();
    }
    #pragma unroll
    for (int i = 0; i < 4; ++i) {
        int s = r0 + ty*4 + i;
        size_t g = (size_t)b*SS + s;
        #pragma unroll
        for (int j = 0; j < 4; ++j) {
            int c = c0 + tx*4 + j;
            float ctx = acc[i][j];
            float hj  = Hj[g*HH + c];
            msgin[g*VINN + c]        = ctx;
            msgin[g*VINN + HH + c]   = hj;
            msgin[g*VINN + 2*HH + c] = ctx*hj;
        }
    }
}

// ---------------- Kernels 4/5: tiled f32 GEMM with fused epilogue ----------
// MODE 0: C = relu(A@B + bias)      MODE 1: C = alpha*(A@B + bias)
template<int MODE>
__global__ __launch_bounds__(256) void k_gemm(
    const float* __restrict__ A, const float* __restrict__ Bm,
    const float* __restrict__ bias, float* __restrict__ C,
    int M, int N, int K, const float* __restrict__ alpha_p)
{
    __shared__ float sA[64][20];
    __shared__ float sB[16][64];
    int tid = threadIdx.x;
    int tx = tid & 15, ty = tid >> 4;
    int r0 = blockIdx.y * 64, c0 = blockIdx.x * 64;
    float acc[4][4] = {};
    for (int kb = 0; kb < K; kb += 16) {
        int idx = tid * 4;
        int ra = idx >> 4, ka = idx & 15;
        *(float4*)&sA[ra][ka] = *(const float4*)(A + (size_t)(r0+ra)*K + kb + ka);
        int kbb = idx >> 6, cb = idx & 63;
        *(float4*)&sB[kbb][cb] = *(const float4*)(Bm + (size_t)(kb+kbb)*N + c0 + cb);
        __syncthreads();
        #pragma unroll
        for (int kk = 0; kk < 16; ++kk) {
            float a[4];
            #pragma unroll
            for (int i = 0; i < 4; ++i) a[i] = sA[ty*4+i][kk];
            float4 bv = *(const float4*)&sB[kk][tx*4];
            float bbv[4] = {bv.x, bv.y, bv.z, bv.w};
            #pragma unroll
            for (int i = 0; i < 4; ++i)
                #pragma unroll
                for (int j = 0; j < 4; ++j)
                    acc[i][j] = fmaf(a[i], bbv[j], acc[i][j]);
        }
        __syncthreads();
    }
    float alpha = (MODE == 1) ? alpha_p[0] : 1.0f;
    #pragma unroll
    for (int i = 0; i < 4; ++i) {
        int r = r0 + ty*4 + i;
        #pragma unroll
        for (int j = 0; j < 4; ++j) {
            int c = c0 + tx*4 + j;
            float v = acc[i][j] + bias[c];
            if (MODE == 0) v = fmaxf(v, 0.f);
            else           v = alpha * v;
            C[(size_t)r*N + c] = v;
        }
    }
}

extern "C" void kernel_launch(void* const* d_in, const int* in_sizes, int n_in,
                              void* d_out, int out_size, void* d_ws, size_t ws_size,
                              hipStream_t stream)
{
    const float* Hj   = (const float*)d_in[0];
    const float* Hi   = (const float*)d_in[1];
    const float* mask = (const float*)d_in[2];
    const float* Wpj  = (const float*)d_in[3];
    const float* Wpi  = (const float*)d_in[4];
    const float* W1   = (const float*)d_in[5];
    const float* b1   = (const float*)d_in[6];
    const float* W2   = (const float*)d_in[7];
    const float* b2   = (const float*)d_in[8];
    const float* Wv1  = (const float*)d_in[9];
    const float* bv1  = (const float*)d_in[10];
    const float* Wv2  = (const float*)d_in[11];
    const float* bv2  = (const float*)d_in[12];
    const float* alpha = (const float*)d_in[13];
    float* out = (float*)d_out;

    float* ws = (float*)d_ws;
    const int NR = BB*SS;                 // 2048
    float* Zj    = ws;                     ws += (size_t)NR*DD;
    float* Zi    = ws;                     ws += (size_t)NR*DD;
    float* Tj    = ws;                     ws += (size_t)NR*HIDD;
    float* Ti    = ws;                     ws += (size_t)NR*HIDD;
    float* probs = ws;                     ws += (size_t)NR*SS;
    float* msgin = ws;                     ws += (size_t)NR*VINN;
    float* Y1    = ws;                     ws += (size_t)NR*VHIDD;

    k_proj<<<NR, 256, 0, stream>>>(Hj, Hi, Wpj, Wpi, W1, Zj, Zi, Tj, Ti);
    k_attn<<<NR, 256, 0, stream>>>(Zj, Zi, Tj, Ti, W1, b1, W2, b2, mask, probs);
    k_ctx<<<dim3(HH/64, SS/64, BB), 256, 0, stream>>>(probs, Hi, Hj, msgin);
    k_gemm<0><<<dim3(VHIDD/64, NR/64), 256, 0, stream>>>(msgin, Wv1, bv1, Y1,
                                                         NR, VHIDD, VINN, alpha);
    k_gemm<1><<<dim3(HH/64, NR/64), 256, 0, stream>>>(Y1, Wv2, bv2, out,
                                                      NR, HH, VHIDD, alpha);
}

// Round 2
// 589.140 us; speedup vs baseline: 1.2931x; 1.2931x over previous
//
#include <hip/hip_runtime.h>
#include <math.h>

#define BB   2
#define SS   1024
#define HH   768
#define DD   24
#define HIDD 96
#define VINN 2304   // 3*H
#define VHIDD 768

typedef __attribute__((ext_vector_type(8))) short short8;
typedef __attribute__((ext_vector_type(4))) float floatx4;

static __device__ inline unsigned short f2bf(float x) {
    unsigned int u = __float_as_uint(x);
    u = (u + 0x7FFFu + ((u >> 16) & 1u)) >> 16;
    return (unsigned short)u;
}
static __device__ inline unsigned int pack2(float a, float b) {
    return (unsigned int)f2bf(a) | ((unsigned int)f2bf(b) << 16);
}

// ---------------- Kernel 1: projections Zj,Zi (H->D) and tj,ti (D->HID) ----
__global__ __launch_bounds__(256) void k_proj(
    const float* __restrict__ Hj, const float* __restrict__ Hi,
    const float* __restrict__ Wpj, const float* __restrict__ Wpi,
    const float* __restrict__ W1,
    float* __restrict__ Zj, float* __restrict__ Zi,
    float* __restrict__ Tj, float* __restrict__ Ti)
{
    int row = blockIdx.x;           // b*S + s
    int tid = threadIdx.x;
    __shared__ float sHj[HH], sHi[HH], sZ[2*DD];
    for (int k = tid; k < HH; k += 256) {
        sHj[k] = Hj[(size_t)row*HH + k];
        sHi[k] = Hi[(size_t)row*HH + k];
    }
    __syncthreads();
    int wave = tid >> 6, lane = tid & 63;
    for (int o = wave; o < 2*DD; o += 4) {
        int d = (o < DD) ? o : o - DD;
        const float* hrow = (o < DD) ? sHj : sHi;
        const float* wp   = (o < DD) ? Wpj : Wpi;
        float acc = 0.f;
        for (int k = lane; k < HH; k += 64)
            acc = fmaf(hrow[k], wp[k*DD + d], acc);
        #pragma unroll
        for (int off = 32; off; off >>= 1) acc += __shfl_down(acc, off, 64);
        if (lane == 0) sZ[o] = acc;
    }
    __syncthreads();
    if (tid < 2*DD) {
        float z = sZ[tid];
        if (tid < DD) Zj[(size_t)row*DD + tid]      = z;
        else          Zi[(size_t)row*DD + tid - DD] = z;
    }
    if (tid < 2*HIDD) {
        int h = tid % HIDD, which = tid / HIDD;   // 0 -> tj (W1a), 1 -> ti (W1b)
        const float* zz = which ? (sZ + DD) : sZ;
        const float* w  = W1 + (which ? DD*HIDD : 0);
        float acc = 0.f;
        #pragma unroll
        for (int d = 0; d < DD; ++d) acc = fmaf(zz[d], w[d*HIDD + h], acc);
        if (which == 0) Tj[(size_t)row*HIDD + h] = acc;
        else            Ti[(size_t)row*HIDD + h] = acc;
    }
}

// ---------------- Kernel 2: MFMA logits + softmax -> probs -----------------
// One block per (b,s). Per-s GEMM: A[t, 0:96] = [p|q|Zi|1|0pad] (bf16),
// B[k, h]   = [W1c; W1d; W1b; tj_s+b1; 0pad] (bf16, stored transposed [h][k]).
// acc[t,h] = v (pre-relu). logit[t] = sum_h relu(v)*W2[h]. Then softmax.
#define KP 96          // padded K
#define LSTR 104       // LDS row stride in ushorts (96 + 8 pad)
#define TC 128         // t-chunk
__global__ __launch_bounds__(256) void k_attn(
    const float* __restrict__ Zj, const float* __restrict__ Zi,
    const float* __restrict__ Tj,
    const float* __restrict__ W1, const float* __restrict__ b1,
    const float* __restrict__ W2,
    const float* __restrict__ mask, float* __restrict__ probs)
{
    int row = blockIdx.x;       // b*S + s
    int b = row >> 10;
    int tid = threadIdx.x;
    int lane = tid & 63, wv = tid >> 6;
    int quad = lane >> 4, col = lane & 15;

    __shared__ __align__(16) unsigned short sB[HIDD][LSTR];   // [h][k]
    __shared__ __align__(16) unsigned short sA[TC][LSTR];     // [t_loc][k]
    __shared__ __align__(16) float sLog[SS];
    __shared__ float sZj[DD];
    __shared__ float sW2[HIDD];
    __shared__ float sRed[4];

    // ---- build B (bf16, transposed) ----
    // B rows k: 0..23 = W1c (W1 rows 48..71), 24..47 = W1d (rows 72..95),
    //           48..71 = W1b (rows 24..47), 72 = Tj[row]+b1, 73..95 = 0
    for (int i = tid; i < 3*DD*HIDD; i += 256) {
        int part = i / (DD*HIDD); int r = i % (DD*HIDD);
        int d = r / HIDD, h2 = r % HIDD;
        int srow = (part == 0) ? (48 + d) : (part == 1) ? (72 + d) : (24 + d);
        sB[h2][part*DD + d] = f2bf(W1[srow*HIDD + h2]);
    }
    if (tid < HIDD) {
        sB[tid][72] = f2bf(Tj[(size_t)row*HIDD + tid] + b1[tid]);
        sW2[tid] = W2[tid];
    }
    for (int i = tid; i < HIDD*23; i += 256) {
        int h2 = i / 23, k = 73 + i % 23;
        sB[h2][k] = 0;
    }
    if (tid < DD) sZj[tid] = Zj[(size_t)row*DD + tid];
    __syncthreads();

    // ---- hoist B fragments + W2 into registers ----
    short8 bfr[6][3];
    #pragma unroll
    for (int nf = 0; nf < 6; ++nf)
        #pragma unroll
        for (int ks = 0; ks < 3; ++ks)
            bfr[nf][ks] = *(const short8*)&sB[nf*16 + col][ks*32 + quad*8];
    float w2r[6];
    #pragma unroll
    for (int nf = 0; nf < 6; ++nf) w2r[nf] = sW2[col + nf*16];

    // ---- chunked K-loop over t ----
    int t_loc = tid >> 1, hh = tid & 1;
    for (int chunk = 0; chunk < SS/TC; ++chunk) {
        // construct A chunk: threads pair up per t-row
        {
            int t = chunk*TC + t_loc;
            const float4* zr = (const float4*)(Zi + ((size_t)((b<<10) + t))*DD);
            float4 z4[6];
            #pragma unroll
            for (int i = 0; i < 6; ++i) z4[i] = zr[i];
            float z[24];
            #pragma unroll
            for (int i = 0; i < 6; ++i) {
                z[4*i+0] = z4[i].x; z[4*i+1] = z4[i].y;
                z[4*i+2] = z4[i].z; z[4*i+3] = z4[i].w;
            }
            if (hh == 0) {
                // k 0..23 = p, 24..47 = q
                #pragma unroll
                for (int g = 0; g < 3; ++g) {
                    uint4 w;
                    w.x = pack2(sZj[8*g+0]*z[8*g+0], sZj[8*g+1]*z[8*g+1]);
                    w.y = pack2(sZj[8*g+2]*z[8*g+2], sZj[8*g+3]*z[8*g+3]);
                    w.z = pack2(sZj[8*g+4]*z[8*g+4], sZj[8*g+5]*z[8*g+5]);
                    w.w = pack2(sZj[8*g+6]*z[8*g+6], sZj[8*g+7]*z[8*g+7]);
                    *(uint4*)&sA[t_loc][8*g] = w;
                }
                #pragma unroll
                for (int g = 0; g < 3; ++g) {
                    uint4 w;
                    w.x = pack2(fabsf(sZj[8*g+0]-z[8*g+0]), fabsf(sZj[8*g+1]-z[8*g+1]));
                    w.y = pack2(fabsf(sZj[8*g+2]-z[8*g+2]), fabsf(sZj[8*g+3]-z[8*g+3]));
                    w.z = pack2(fabsf(sZj[8*g+4]-z[8*g+4]), fabsf(sZj[8*g+5]-z[8*g+5]));
                    w.w = pack2(fabsf(sZj[8*g+6]-z[8*g+6]), fabsf(sZj[8*g+7]-z[8*g+7]));
                    *(uint4*)&sA[t_loc][24 + 8*g] = w;
                }
            } else {
                // k 48..71 = Zi, 72 = 1.0, 73..95 = 0
                #pragma unroll
                for (int g = 0; g < 3; ++g) {
                    uint4 w;
                    w.x = pack2(z[8*g+0], z[8*g+1]);
                    w.y = pack2(z[8*g+2], z[8*g+3]);
                    w.z = pack2(z[8*g+4], z[8*g+5]);
                    w.w = pack2(z[8*g+6], z[8*g+7]);
                    *(uint4*)&sA[t_loc][48 + 8*g] = w;
                }
                uint4 w0; w0.x = pack2(1.0f, 0.0f); w0.y = 0; w0.z = 0; w0.w = 0;
                *(uint4*)&sA[t_loc][72] = w0;
                uint4 zz; zz.x = 0; zz.y = 0; zz.z = 0; zz.w = 0;
                *(uint4*)&sA[t_loc][80] = zz;
                *(uint4*)&sA[t_loc][88] = zz;
            }
        }
        __syncthreads();

        // MFMA: each wave owns 2 M-tiles of 16 t
        #pragma unroll
        for (int mt = 0; mt < 2; ++mt) {
            int arow = (wv*2 + mt)*16 + col;
            short8 a0 = *(const short8*)&sA[arow][quad*8];
            short8 a1 = *(const short8*)&sA[arow][32 + quad*8];
            short8 a2 = *(const short8*)&sA[arow][64 + quad*8];
            float s0 = 0.f, s1 = 0.f, s2 = 0.f, s3 = 0.f;
            #pragma unroll
            for (int nf = 0; nf < 6; ++nf) {
                floatx4 acc = {0.f, 0.f, 0.f, 0.f};
                acc = __builtin_amdgcn_mfma_f32_16x16x32_bf16(a0, bfr[nf][0], acc, 0, 0, 0);
                acc = __builtin_amdgcn_mfma_f32_16x16x32_bf16(a1, bfr[nf][1], acc, 0, 0, 0);
                acc = __builtin_amdgcn_mfma_f32_16x16x32_bf16(a2, bfr[nf][2], acc, 0, 0, 0);
                float w2v = w2r[nf];
                s0 = fmaf(fmaxf(acc[0], 0.f), w2v, s0);
                s1 = fmaf(fmaxf(acc[1], 0.f), w2v, s1);
                s2 = fmaf(fmaxf(acc[2], 0.f), w2v, s2);
                s3 = fmaf(fmaxf(acc[3], 0.f), w2v, s3);
            }
            // reduce over the 16 cols (lanes within each quad group)
            #pragma unroll
            for (int m = 1; m < 16; m <<= 1) {
                s0 += __shfl_xor(s0, m, 64);
                s1 += __shfl_xor(s1, m, 64);
                s2 += __shfl_xor(s2, m, 64);
                s3 += __shfl_xor(s3, m, 64);
            }
            if (col == 0) {
                float4 o; o.x = s0; o.y = s1; o.z = s2; o.w = s3;
                *(float4*)&sLog[chunk*TC + (wv*2 + mt)*16 + quad*4] = o;
            }
        }
        __syncthreads();
    }

    // ---- softmax over t (S=1024) within the block ----
    float lv[4];
    #pragma unroll
    for (int i = 0; i < 4; ++i) {
        int t = tid + i*256;
        lv[i] = sLog[t] + (1.0f - mask[(size_t)(b<<10) + t]) * (-3.402823466e+38f);
    }
    float m = fmaxf(fmaxf(lv[0], lv[1]), fmaxf(lv[2], lv[3]));
    #pragma unroll
    for (int off = 32; off; off >>= 1) m = fmaxf(m, __shfl_down(m, off, 64));
    if (lane == 0) sRed[wv] = m;
    __syncthreads();
    float M = fmaxf(fmaxf(sRed[0], sRed[1]), fmaxf(sRed[2], sRed[3]));
    float e[4]; float ssum = 0.f;
    #pragma unroll
    for (int i = 0; i < 4; ++i) { e[i] = expf(lv[i] - M); ssum += e[i]; }
    #pragma unroll
    for (int off = 32; off; off >>= 1) ssum += __shfl_down(ssum, off, 64);
    __syncthreads();
    if (lane == 0) sRed[wv] = ssum;
    __syncthreads();
    float inv = 1.0f / (sRed[0] + sRed[1] + sRed[2] + sRed[3]);
    #pragma unroll
    for (int i = 0; i < 4; ++i)
        probs[(size_t)row*SS + tid + i*256] = e[i] * inv;
}

// ---------------- Kernel 3: ctx = probs @ H_i, epilogue builds msg_in ------
__global__ __launch_bounds__(256) void k_ctx(
    const float* __restrict__ probs, const float* __restrict__ Hi,
    const float* __restrict__ Hj, float* __restrict__ msgin)
{
    int b = blockIdx.z;
    const float* A  = probs + (size_t)b*SS*SS;
    const float* Bm = Hi    + (size_t)b*SS*HH;
    __shared__ float sA[64][20];
    __shared__ float sB[16][64];
    int tid = threadIdx.x;
    int tx = tid & 15, ty = tid >> 4;
    int r0 = blockIdx.y * 64, c0 = blockIdx.x * 64;
    float acc[4][4] = {};
    for (int kb = 0; kb < SS; kb += 16) {
        int idx = tid * 4;
        int ra = idx >> 4, ka = idx & 15;
        *(float4*)&sA[ra][ka] = *(const float4*)(A + (size_t)(r0+ra)*SS + kb + ka);
        int kbb = idx >> 6, cb = idx & 63;
        *(float4*)&sB[kbb][cb] = *(const float4*)(Bm + (size_t)(kb+kbb)*HH + c0 + cb);
        __syncthreads();
        #pragma unroll
        for (int kk = 0; kk < 16; ++kk) {
            float a[4];
            #pragma unroll
            for (int i = 0; i < 4; ++i) a[i] = sA[ty*4+i][kk];
            float4 bv = *(const float4*)&sB[kk][tx*4];
            float bbv[4] = {bv.x, bv.y, bv.z, bv.w};
            #pragma unroll
            for (int i = 0; i < 4; ++i)
                #pragma unroll
                for (int j = 0; j < 4; ++j)
                    acc[i][j] = fmaf(a[i], bbv[j], acc[i][j]);
        }
        __syncthreads();
    }
    #pragma unroll
    for (int i = 0; i < 4; ++i) {
        int s = r0 + ty*4 + i;
        size_t g = (size_t)b*SS + s;
        #pragma unroll
        for (int j = 0; j < 4; ++j) {
            int c = c0 + tx*4 + j;
            float ctx = acc[i][j];
            float hj  = Hj[g*HH + c];
            msgin[g*VINN + c]        = ctx;
            msgin[g*VINN + HH + c]   = hj;
            msgin[g*VINN + 2*HH + c] = ctx*hj;
        }
    }
}

// ---------------- Kernels 4/5: tiled f32 GEMM with fused epilogue ----------
// MODE 0: C = relu(A@B + bias)      MODE 1: C = alpha*(A@B + bias)
template<int MODE>
__global__ __launch_bounds__(256) void k_gemm(
    const float* __restrict__ A, const float* __restrict__ Bm,
    const float* __restrict__ bias, float* __restrict__ C,
    int M, int N, int K, const float* __restrict__ alpha_p)
{
    __shared__ float sA[64][20];
    __shared__ float sB[16][64];
    int tid = threadIdx.x;
    int tx = tid & 15, ty = tid >> 4;
    int r0 = blockIdx.y * 64, c0 = blockIdx.x * 64;
    float acc[4][4] = {};
    for (int kb = 0; kb < K; kb += 16) {
        int idx = tid * 4;
        int ra = idx >> 4, ka = idx & 15;
        *(float4*)&sA[ra][ka] = *(const float4*)(A + (size_t)(r0+ra)*K + kb + ka);
        int kbb = idx >> 6, cb = idx & 63;
        *(float4*)&sB[kbb][cb] = *(const float4*)(Bm + (size_t)(kb+kbb)*N + c0 + cb);
        __syncthreads();
        #pragma unroll
        for (int kk = 0; kk < 16; ++kk) {
            float a[4];
            #pragma unroll
            for (int i = 0; i < 4; ++i) a[i] = sA[ty*4+i][kk];
            float4 bv = *(const float4*)&sB[kk][tx*4];
            float bbv[4] = {bv.x, bv.y, bv.z, bv.w};
            #pragma unroll
            for (int i = 0; i < 4; ++i)
                #pragma unroll
                for (int j = 0; j < 4; ++j)
                    acc[i][j] = fmaf(a[i], bbv[j], acc[i][j]);
        }
        __syncthreads();
    }
    float alpha = (MODE == 1) ? alpha_p[0] : 1.0f;
    #pragma unroll
    for (int i = 0; i < 4; ++i) {
        int r = r0 + ty*4 + i;
        #pragma unroll
        for (int j = 0; j < 4; ++j) {
            int c = c0 + tx*4 + j;
            float v = acc[i][j] + bias[c];
            if (MODE == 0) v = fmaxf(v, 0.f);
            else           v = alpha * v;
            C[(size_t)r*N + c] = v;
        }
    }
}

extern "C" void kernel_launch(void* const* d_in, const int* in_sizes, int n_in,
                              void* d_out, int out_size, void* d_ws, size_t ws_size,
                              hipStream_t stream)
{
    const float* Hj   = (const float*)d_in[0];
    const float* Hi   = (const float*)d_in[1];
    const float* mask = (const float*)d_in[2];
    const float* Wpj  = (const float*)d_in[3];
    const float* Wpi  = (const float*)d_in[4];
    const float* W1   = (const float*)d_in[5];
    const float* b1   = (const float*)d_in[6];
    const float* W2   = (const float*)d_in[7];
    const float* b2   = (const float*)d_in[8];   // softmax-shift-invariant: unused
    const float* Wv1  = (const float*)d_in[9];
    const float* bv1  = (const float*)d_in[10];
    const float* Wv2  = (const float*)d_in[11];
    const float* bv2  = (const float*)d_in[12];
    const float* alpha = (const float*)d_in[13];
    float* out = (float*)d_out;
    (void)b2;

    float* ws = (float*)d_ws;
    const int NR = BB*SS;                 // 2048
    float* Zj    = ws;                     ws += (size_t)NR*DD;
    float* Zi    = ws;                     ws += (size_t)NR*DD;
    float* Tj    = ws;                     ws += (size_t)NR*HIDD;
    float* Ti    = ws;                     ws += (size_t)NR*HIDD;
    float* probs = ws;                     ws += (size_t)NR*SS;
    float* msgin = ws;                     ws += (size_t)NR*VINN;
    float* Y1    = ws;                     ws += (size_t)NR*VHIDD;

    k_proj<<<NR, 256, 0, stream>>>(Hj, Hi, Wpj, Wpi, W1, Zj, Zi, Tj, Ti);
    k_attn<<<NR, 256, 0, stream>>>(Zj, Zi, Tj, W1, b1, W2, mask, probs);
    k_ctx<<<dim3(HH/64, SS/64, BB), 256, 0, stream>>>(probs, Hi, Hj, msgin);
    k_gemm<0><<<dim3(VHIDD/64, NR/64), 256, 0, stream>>>(msgin, Wv1, bv1, Y1,
                                                         NR, VHIDD, VINN, alpha);
    k_gemm<1><<<dim3(HH/64, NR/64), 256, 0, stream>>>(Y1, Wv2, bv2, out,
                                                      NR, HH, VHIDD, alpha);
}

// Round 3
// 486.902 us; speedup vs baseline: 1.5647x; 1.2100x over previous
//
#include <hip/hip_runtime.h>
#include <math.h>

#define BB   2
#define SS   1024
#define HH   768
#define DD   24
#define HIDD 96
#define VINN 2304   // 3*H
#define VHIDD 768

typedef __attribute__((ext_vector_type(8))) short short8;
typedef __attribute__((ext_vector_type(4))) float floatx4;

static __device__ inline unsigned short f2bf(float x) {
    unsigned int u = __float_as_uint(x);
    u = (u + 0x7FFFu + ((u >> 16) & 1u)) >> 16;
    return (unsigned short)u;
}
static __device__ inline unsigned int pack2(float a, float b) {
    return (unsigned int)f2bf(a) | ((unsigned int)f2bf(b) << 16);
}

// ---------------- Kernel 0: f32 -> bf16 transpose-convert ------------------
// in: [z][R][C] f32  ->  out: [z][C][R] bf16.  R, C multiples of 32.
__global__ __launch_bounds__(256) void k_tconv(
    const float* __restrict__ in, unsigned short* __restrict__ out,
    int R, int C)
{
    size_t zoff = (size_t)blockIdx.z * R * C;
    in += zoff; out += zoff;
    __shared__ float tile[32][33];
    int r0 = blockIdx.y * 32, c0 = blockIdx.x * 32;
    int tc = threadIdx.x & 31, tr = threadIdx.x >> 5;   // 8 rows per pass
    #pragma unroll
    for (int i = 0; i < 4; ++i)
        tile[tr + i*8][tc] = in[(size_t)(r0 + tr + i*8)*C + c0 + tc];
    __syncthreads();
    #pragma unroll
    for (int i = 0; i < 4; ++i)
        out[(size_t)(c0 + tr + i*8)*R + r0 + tc] = f2bf(tile[tc][tr + i*8]);
}

// ---------------- Kernel 1: projections Zj,Zi (H->D) and tj,ti (D->HID) ----
__global__ __launch_bounds__(256) void k_proj(
    const float* __restrict__ Hj, const float* __restrict__ Hi,
    const float* __restrict__ Wpj, const float* __restrict__ Wpi,
    const float* __restrict__ W1,
    float* __restrict__ Zj, float* __restrict__ Zi,
    float* __restrict__ Tj)
{
    int row = blockIdx.x;           // b*S + s
    int tid = threadIdx.x;
    __shared__ float sHj[HH], sHi[HH], sZ[2*DD];
    for (int k = tid; k < HH; k += 256) {
        sHj[k] = Hj[(size_t)row*HH + k];
        sHi[k] = Hi[(size_t)row*HH + k];
    }
    __syncthreads();
    int wave = tid >> 6, lane = tid & 63;
    for (int o = wave; o < 2*DD; o += 4) {
        int d = (o < DD) ? o : o - DD;
        const float* hrow = (o < DD) ? sHj : sHi;
        const float* wp   = (o < DD) ? Wpj : Wpi;
        float acc = 0.f;
        for (int k = lane; k < HH; k += 64)
            acc = fmaf(hrow[k], wp[k*DD + d], acc);
        #pragma unroll
        for (int off = 32; off; off >>= 1) acc += __shfl_down(acc, off, 64);
        if (lane == 0) sZ[o] = acc;
    }
    __syncthreads();
    if (tid < 2*DD) {
        float z = sZ[tid];
        if (tid < DD) Zj[(size_t)row*DD + tid]      = z;
        else          Zi[(size_t)row*DD + tid - DD] = z;
    }
    if (tid < HIDD) {
        float acc = 0.f;
        #pragma unroll
        for (int d = 0; d < DD; ++d) acc = fmaf(sZ[d], W1[d*HIDD + tid], acc);
        Tj[(size_t)row*HIDD + tid] = acc;
    }
}

// ---------------- Kernel 2: MFMA logits + softmax -> probs (bf16) ----------
#define LSTR 104       // LDS row stride in ushorts (96 + 8 pad)
#define TC 128         // t-chunk
__global__ __launch_bounds__(256) void k_attn(
    const float* __restrict__ Zj, const float* __restrict__ Zi,
    const float* __restrict__ Tj,
    const float* __restrict__ W1, const float* __restrict__ b1,
    const float* __restrict__ W2,
    const float* __restrict__ mask, unsigned short* __restrict__ probs)
{
    int row = blockIdx.x;       // b*S + s
    int b = row >> 10;
    int tid = threadIdx.x;
    int lane = tid & 63, wv = tid >> 6;
    int quad = lane >> 4, col = lane & 15;

    __shared__ __align__(16) unsigned short sB[HIDD][LSTR];   // [h][k]
    __shared__ __align__(16) unsigned short sA[TC][LSTR];     // [t_loc][k]
    __shared__ __align__(16) float sLog[SS];
    __shared__ float sZj[DD];
    __shared__ float sW2[HIDD];
    __shared__ float sRed[4];

    // B rows k: 0..23 = W1c (W1 rows 48..71), 24..47 = W1d (rows 72..95),
    //           48..71 = W1b (rows 24..47), 72 = Tj[row]+b1, 73..95 = 0
    for (int i = tid; i < 3*DD*HIDD; i += 256) {
        int part = i / (DD*HIDD); int r = i % (DD*HIDD);
        int d = r / HIDD, h2 = r % HIDD;
        int srow = (part == 0) ? (48 + d) : (part == 1) ? (72 + d) : (24 + d);
        sB[h2][part*DD + d] = f2bf(W1[srow*HIDD + h2]);
    }
    if (tid < HIDD) {
        sB[tid][72] = f2bf(Tj[(size_t)row*HIDD + tid] + b1[tid]);
        sW2[tid] = W2[tid];
    }
    for (int i = tid; i < HIDD*23; i += 256) {
        int h2 = i / 23, k = 73 + i % 23;
        sB[h2][k] = 0;
    }
    if (tid < DD) sZj[tid] = Zj[(size_t)row*DD + tid];
    __syncthreads();

    short8 bfr[6][3];
    #pragma unroll
    for (int nf = 0; nf < 6; ++nf)
        #pragma unroll
        for (int ks = 0; ks < 3; ++ks)
            bfr[nf][ks] = *(const short8*)&sB[nf*16 + col][ks*32 + quad*8];
    float w2r[6];
    #pragma unroll
    for (int nf = 0; nf < 6; ++nf) w2r[nf] = sW2[col + nf*16];

    int t_loc = tid >> 1, hh = tid & 1;
    for (int chunk = 0; chunk < SS/TC; ++chunk) {
        {
            int t = chunk*TC + t_loc;
            const float4* zr = (const float4*)(Zi + ((size_t)((b<<10) + t))*DD);
            float4 z4[6];
            #pragma unroll
            for (int i = 0; i < 6; ++i) z4[i] = zr[i];
            float z[24];
            #pragma unroll
            for (int i = 0; i < 6; ++i) {
                z[4*i+0] = z4[i].x; z[4*i+1] = z4[i].y;
                z[4*i+2] = z4[i].z; z[4*i+3] = z4[i].w;
            }
            if (hh == 0) {
                #pragma unroll
                for (int g = 0; g < 3; ++g) {
                    uint4 w;
                    w.x = pack2(sZj[8*g+0]*z[8*g+0], sZj[8*g+1]*z[8*g+1]);
                    w.y = pack2(sZj[8*g+2]*z[8*g+2], sZj[8*g+3]*z[8*g+3]);
                    w.z = pack2(sZj[8*g+4]*z[8*g+4], sZj[8*g+5]*z[8*g+5]);
                    w.w = pack2(sZj[8*g+6]*z[8*g+6], sZj[8*g+7]*z[8*g+7]);
                    *(uint4*)&sA[t_loc][8*g] = w;
                }
                #pragma unroll
                for (int g = 0; g < 3; ++g) {
                    uint4 w;
                    w.x = pack2(fabsf(sZj[8*g+0]-z[8*g+0]), fabsf(sZj[8*g+1]-z[8*g+1]));
                    w.y = pack2(fabsf(sZj[8*g+2]-z[8*g+2]), fabsf(sZj[8*g+3]-z[8*g+3]));
                    w.z = pack2(fabsf(sZj[8*g+4]-z[8*g+4]), fabsf(sZj[8*g+5]-z[8*g+5]));
                    w.w = pack2(fabsf(sZj[8*g+6]-z[8*g+6]), fabsf(sZj[8*g+7]-z[8*g+7]));
                    *(uint4*)&sA[t_loc][24 + 8*g] = w;
                }
            } else {
                #pragma unroll
                for (int g = 0; g < 3; ++g) {
                    uint4 w;
                    w.x = pack2(z[8*g+0], z[8*g+1]);
                    w.y = pack2(z[8*g+2], z[8*g+3]);
                    w.z = pack2(z[8*g+4], z[8*g+5]);
                    w.w = pack2(z[8*g+6], z[8*g+7]);
                    *(uint4*)&sA[t_loc][48 + 8*g] = w;
                }
                uint4 w0; w0.x = pack2(1.0f, 0.0f); w0.y = 0; w0.z = 0; w0.w = 0;
                *(uint4*)&sA[t_loc][72] = w0;
                uint4 zz; zz.x = 0; zz.y = 0; zz.z = 0; zz.w = 0;
                *(uint4*)&sA[t_loc][80] = zz;
                *(uint4*)&sA[t_loc][88] = zz;
            }
        }
        __syncthreads();

        #pragma unroll
        for (int mt = 0; mt < 2; ++mt) {
            int arow = (wv*2 + mt)*16 + col;
            short8 a0 = *(const short8*)&sA[arow][quad*8];
            short8 a1 = *(const short8*)&sA[arow][32 + quad*8];
            short8 a2 = *(const short8*)&sA[arow][64 + quad*8];
            float s0 = 0.f, s1 = 0.f, s2 = 0.f, s3 = 0.f;
            #pragma unroll
            for (int nf = 0; nf < 6; ++nf) {
                floatx4 acc = {0.f, 0.f, 0.f, 0.f};
                acc = __builtin_amdgcn_mfma_f32_16x16x32_bf16(a0, bfr[nf][0], acc, 0, 0, 0);
                acc = __builtin_amdgcn_mfma_f32_16x16x32_bf16(a1, bfr[nf][1], acc, 0, 0, 0);
                acc = __builtin_amdgcn_mfma_f32_16x16x32_bf16(a2, bfr[nf][2], acc, 0, 0, 0);
                float w2v = w2r[nf];
                s0 = fmaf(fmaxf(acc[0], 0.f), w2v, s0);
                s1 = fmaf(fmaxf(acc[1], 0.f), w2v, s1);
                s2 = fmaf(fmaxf(acc[2], 0.f), w2v, s2);
                s3 = fmaf(fmaxf(acc[3], 0.f), w2v, s3);
            }
            #pragma unroll
            for (int m = 1; m < 16; m <<= 1) {
                s0 += __shfl_xor(s0, m, 64);
                s1 += __shfl_xor(s1, m, 64);
                s2 += __shfl_xor(s2, m, 64);
                s3 += __shfl_xor(s3, m, 64);
            }
            if (col == 0) {
                float4 o; o.x = s0; o.y = s1; o.z = s2; o.w = s3;
                *(float4*)&sLog[chunk*TC + (wv*2 + mt)*16 + quad*4] = o;
            }
        }
        __syncthreads();
    }

    // ---- softmax ----
    float lv[4];
    #pragma unroll
    for (int i = 0; i < 4; ++i) {
        int t = tid + i*256;
        lv[i] = sLog[t] + (1.0f - mask[(size_t)(b<<10) + t]) * (-3.402823466e+38f);
    }
    float m = fmaxf(fmaxf(lv[0], lv[1]), fmaxf(lv[2], lv[3]));
    #pragma unroll
    for (int off = 32; off; off >>= 1) m = fmaxf(m, __shfl_down(m, off, 64));
    if (lane == 0) sRed[wv] = m;
    __syncthreads();
    float M = fmaxf(fmaxf(sRed[0], sRed[1]), fmaxf(sRed[2], sRed[3]));
    float e[4]; float ssum = 0.f;
    #pragma unroll
    for (int i = 0; i < 4; ++i) { e[i] = expf(lv[i] - M); ssum += e[i]; }
    #pragma unroll
    for (int off = 32; off; off >>= 1) ssum += __shfl_down(ssum, off, 64);
    __syncthreads();
    if (lane == 0) sRed[wv] = ssum;
    __syncthreads();
    float inv = 1.0f / (sRed[0] + sRed[1] + sRed[2] + sRed[3]);
    #pragma unroll
    for (int i = 0; i < 4; ++i)
        probs[(size_t)row*SS + tid + i*256] = f2bf(e[i] * inv);
}

// ---------------- Kernel 3: bf16 MFMA GEMM, 128Mx64N tile, BK=64 -----------
// A: [rows][K] bf16 row-major.  BT: [N][K] bf16 (B transposed, K-major).
// MODE 0: ctx -> msgin builder (writes ctx | hj | ctx*hj, bf16)
// MODE 1: Y1 = bf16(relu(A@B + bias))
// MODE 2: out = f32(alpha*(A@B + bias))
template<int MODE>
__global__ __launch_bounds__(256) void k_mgemm(
    const unsigned short* __restrict__ A,
    const unsigned short* __restrict__ BT,
    const float* __restrict__ bias,
    const float* __restrict__ Hj,
    void* __restrict__ Cout,
    int K, const float* __restrict__ alpha_p)
{
    __shared__ __align__(16) unsigned short sA[128][72];
    __shared__ __align__(16) unsigned short sBT[64][72];
    int tid = threadIdx.x;
    int w = tid >> 6, lane = tid & 63;
    int quad = lane >> 4, col = lane & 15;

    int rows_per_batch = gridDim.y * 128;
    size_t aoff  = (size_t)blockIdx.z * rows_per_batch * K;
    size_t btoff = (size_t)blockIdx.z * 768 * K;
    A  += aoff;
    BT += btoff;
    int m0 = blockIdx.y * 128;
    int n0 = blockIdx.x * 64;
    size_t grow0 = (size_t)blockIdx.z * rows_per_batch + m0;

    floatx4 acc[2][4];
    #pragma unroll
    for (int mt = 0; mt < 2; ++mt)
        #pragma unroll
        for (int nt = 0; nt < 4; ++nt)
            acc[mt][nt] = (floatx4){0.f, 0.f, 0.f, 0.f};

    for (int kb = 0; kb < K; kb += 64) {
        #pragma unroll
        for (int i = 0; i < 4; ++i) {
            int c = tid + i*256;
            int row = c >> 3, kc = c & 7;
            *(uint4*)&sA[row][kc*8] =
                *(const uint4*)(A + (size_t)(m0 + row)*K + kb + kc*8);
        }
        #pragma unroll
        for (int i = 0; i < 2; ++i) {
            int c = tid + i*256;
            int row = c >> 3, kc = c & 7;
            *(uint4*)&sBT[row][kc*8] =
                *(const uint4*)(BT + (size_t)(n0 + row)*K + kb + kc*8);
        }
        __syncthreads();
        #pragma unroll
        for (int kt = 0; kt < 2; ++kt) {
            short8 av[2], bv[4];
            #pragma unroll
            for (int mt = 0; mt < 2; ++mt)
                av[mt] = *(const short8*)&sA[w*32 + mt*16 + col][kt*32 + quad*8];
            #pragma unroll
            for (int nt = 0; nt < 4; ++nt)
                bv[nt] = *(const short8*)&sBT[nt*16 + col][kt*32 + quad*8];
            #pragma unroll
            for (int mt = 0; mt < 2; ++mt)
                #pragma unroll
                for (int nt = 0; nt < 4; ++nt)
                    acc[mt][nt] = __builtin_amdgcn_mfma_f32_16x16x32_bf16(
                        av[mt], bv[nt], acc[mt][nt], 0, 0, 0);
        }
        __syncthreads();
    }

    float alpha = (MODE == 2) ? alpha_p[0] : 1.0f;
    #pragma unroll
    for (int mt = 0; mt < 2; ++mt) {
        #pragma unroll
        for (int nt = 0; nt < 4; ++nt) {
            int n = n0 + nt*16 + col;
            #pragma unroll
            for (int r = 0; r < 4; ++r) {
                int m = w*32 + mt*16 + quad*4 + r;
                size_t g = grow0 + m;
                float v = acc[mt][nt][r];
                if (MODE == 0) {
                    float hj = Hj[g*HH + n];
                    unsigned short* msgin = (unsigned short*)Cout;
                    msgin[g*VINN + n]        = f2bf(v);
                    msgin[g*VINN + HH + n]   = f2bf(hj);
                    msgin[g*VINN + 2*HH + n] = f2bf(v*hj);
                } else if (MODE == 1) {
                    ((unsigned short*)Cout)[g*VHIDD + n] =
                        f2bf(fmaxf(v + bias[n], 0.f));
                } else {
                    ((float*)Cout)[g*HH + n] = alpha*(v + bias[n]);
                }
            }
        }
    }
}

extern "C" void kernel_launch(void* const* d_in, const int* in_sizes, int n_in,
                              void* d_out, int out_size, void* d_ws, size_t ws_size,
                              hipStream_t stream)
{
    const float* Hj   = (const float*)d_in[0];
    const float* Hi   = (const float*)d_in[1];
    const float* mask = (const float*)d_in[2];
    const float* Wpj  = (const float*)d_in[3];
    const float* Wpi  = (const float*)d_in[4];
    const float* W1   = (const float*)d_in[5];
    const float* b1   = (const float*)d_in[6];
    const float* W2   = (const float*)d_in[7];
    const float* bv1  = (const float*)d_in[10];
    const float* Wv1  = (const float*)d_in[9];
    const float* Wv2  = (const float*)d_in[11];
    const float* bv2  = (const float*)d_in[12];
    const float* alpha = (const float*)d_in[13];
    float* out = (float*)d_out;

    const int NR = BB*SS;                 // 2048
    char* p = (char*)d_ws;
    auto alloc = [&](size_t bytes) {
        char* r = p; p += (bytes + 255) & ~(size_t)255; return r;
    };
    float* Zj             = (float*)alloc((size_t)NR*DD*4);
    float* Zi             = (float*)alloc((size_t)NR*DD*4);
    float* Tj             = (float*)alloc((size_t)NR*HIDD*4);
    unsigned short* probsb = (unsigned short*)alloc((size_t)NR*SS*2);
    unsigned short* HiT    = (unsigned short*)alloc((size_t)BB*HH*SS*2);
    unsigned short* Wv1T   = (unsigned short*)alloc((size_t)VHIDD*VINN*2);
    unsigned short* Wv2T   = (unsigned short*)alloc((size_t)HH*VHIDD*2);
    unsigned short* msginb = (unsigned short*)alloc((size_t)NR*VINN*2);
    unsigned short* Y1b    = (unsigned short*)alloc((size_t)NR*VHIDD*2);

    k_tconv<<<dim3(VHIDD/32, VINN/32, 1), 256, 0, stream>>>(Wv1, Wv1T, VINN, VHIDD);
    k_tconv<<<dim3(HH/32, VHIDD/32, 1), 256, 0, stream>>>(Wv2, Wv2T, VHIDD, HH);
    k_tconv<<<dim3(HH/32, SS/32, BB), 256, 0, stream>>>(Hi, HiT, SS, HH);
    k_proj<<<NR, 256, 0, stream>>>(Hj, Hi, Wpj, Wpi, W1, Zj, Zi, Tj);
    k_attn<<<NR, 256, 0, stream>>>(Zj, Zi, Tj, W1, b1, W2, mask, probsb);
    // ctx GEMM: per b, M=1024 (s), N=768 (h), K=1024 (t)
    k_mgemm<0><<<dim3(HH/64, SS/128, BB), 256, 0, stream>>>(
        probsb, HiT, nullptr, Hj, msginb, SS, alpha);
    // MLP GEMM1: M=2048, N=768, K=2304
    k_mgemm<1><<<dim3(VHIDD/64, NR/128, 1), 256, 0, stream>>>(
        msginb, Wv1T, bv1, nullptr, Y1b, VINN, alpha);
    // MLP GEMM2: M=2048, N=768, K=768
    k_mgemm<2><<<dim3(HH/64, NR/128, 1), 256, 0, stream>>>(
        Y1b, Wv2T, bv2, nullptr, out, VHIDD, alpha);
}

// Round 4
// 371.605 us; speedup vs baseline: 2.0501x; 1.3103x over previous
//
#include <hip/hip_runtime.h>
#include <math.h>

#define BB   2
#define SS   1024
#define HH   768
#define DD   24
#define HIDD 96
#define VINN 2304   // 3*H
#define VHIDD 768

typedef __attribute__((ext_vector_type(8))) short short8;
typedef __attribute__((ext_vector_type(4))) float floatx4;

static __device__ inline unsigned short f2bf(float x) {
    unsigned int u = __float_as_uint(x);
    u = (u + 0x7FFFu + ((u >> 16) & 1u)) >> 16;
    return (unsigned short)u;
}
static __device__ inline unsigned int pack2(float a, float b) {
    return (unsigned int)f2bf(a) | ((unsigned int)f2bf(b) << 16);
}

// ---------------- Kernel 0: f32 -> bf16 transpose-convert ------------------
// in: [z][R][C] f32  ->  out: [z][C][R] bf16.  R, C multiples of 32.
__global__ __launch_bounds__(256) void k_tconv(
    const float* __restrict__ in, unsigned short* __restrict__ out,
    int R, int C)
{
    size_t zoff = (size_t)blockIdx.z * R * C;
    in += zoff; out += zoff;
    __shared__ float tile[32][33];
    int r0 = blockIdx.y * 32, c0 = blockIdx.x * 32;
    int tc = threadIdx.x & 31, tr = threadIdx.x >> 5;   // 8 rows per pass
    #pragma unroll
    for (int i = 0; i < 4; ++i)
        tile[tr + i*8][tc] = in[(size_t)(r0 + tr + i*8)*C + c0 + tc];
    __syncthreads();
    #pragma unroll
    for (int i = 0; i < 4; ++i)
        out[(size_t)(c0 + tr + i*8)*R + r0 + tc] = f2bf(tile[tc][tr + i*8]);
}

// ---------------- Kernel 1: Z projections via MFMA -------------------------
// Virtual M = 4096: rows 0..2047 -> Zj = Hj@Wpj, rows 2048..4095 -> Zi = Hi@Wpi.
// N = 24 padded to 32 (pad cols never written: n<24 guard). K = 768.
__global__ __launch_bounds__(256) void k_zproj(
    const float* __restrict__ Hj, const float* __restrict__ Hi,
    const float* __restrict__ Wpj, const float* __restrict__ Wpi,
    float* __restrict__ Zj, float* __restrict__ Zi)
{
    __shared__ __align__(16) unsigned short sA[64][72];
    __shared__ __align__(16) unsigned short sBT[32][72];  // rows 24..31 unused
    int tid = threadIdx.x;
    int w = tid >> 6, lane = tid & 63;
    int quad = lane >> 4, col = lane & 15;

    int m0 = blockIdx.x * 64;
    bool isJ = (m0 < BB*SS);
    const float* src = isJ ? Hj : Hi;
    const float* Wp  = isJ ? Wpj : Wpi;
    float* Zo        = isJ ? Zj : Zi;
    int rowbase = isJ ? m0 : (m0 - BB*SS);

    floatx4 acc[2];
    acc[0] = (floatx4){0.f,0.f,0.f,0.f};
    acc[1] = (floatx4){0.f,0.f,0.f,0.f};

    for (int kb = 0; kb < HH; kb += 64) {
        // stage A tile (64 rows x 64 k), f32 -> bf16, coalesced float4
        #pragma unroll
        for (int i = 0; i < 4; ++i) {
            int f4 = tid + i*256;            // 0..1023
            int r = f4 >> 4, c4 = f4 & 15;   // r 0..63, c4 0..15
            float4 v = *(const float4*)(src + (size_t)(rowbase + r)*HH + kb + c4*4);
            uint2 pkt; pkt.x = pack2(v.x, v.y); pkt.y = pack2(v.z, v.w);
            *(uint2*)&sA[r][c4*4] = pkt;
        }
        // stage BT: transpose Wp chunk [64 k][24 n] (1536 contiguous floats)
        {
            const float* wsrc = Wp + (size_t)kb*DD;
            #pragma unroll
            for (int i = 0; i < 6; ++i) {
                int idx = tid + i*256;       // 0..1535
                int k = idx / DD, n = idx % DD;
                sBT[n][k] = f2bf(wsrc[idx]);
            }
        }
        __syncthreads();
        #pragma unroll
        for (int kt = 0; kt < 2; ++kt) {
            short8 av = *(const short8*)&sA[w*16 + col][kt*32 + quad*8];
            #pragma unroll
            for (int nt = 0; nt < 2; ++nt) {
                short8 bv = *(const short8*)&sBT[nt*16 + col][kt*32 + quad*8];
                acc[nt] = __builtin_amdgcn_mfma_f32_16x16x32_bf16(av, bv, acc[nt], 0, 0, 0);
            }
        }
        __syncthreads();
    }
    #pragma unroll
    for (int nt = 0; nt < 2; ++nt) {
        int n = nt*16 + col;
        if (n < DD) {
            #pragma unroll
            for (int r = 0; r < 4; ++r) {
                int m = w*16 + quad*4 + r;
                Zo[(size_t)(rowbase + m)*DD + n] = acc[nt][r];
            }
        }
    }
}

// ---------------- Kernel 2: MFMA logits + softmax -> probs (bf16) ----------
#define LSTR 104       // LDS row stride in ushorts (96 + 8 pad)
#define TC 128         // t-chunk
__global__ __launch_bounds__(256) void k_attn(
    const float* __restrict__ Zj, const float* __restrict__ Zi,
    const float* __restrict__ W1, const float* __restrict__ b1,
    const float* __restrict__ W2,
    const float* __restrict__ mask, unsigned short* __restrict__ probs)
{
    int row = blockIdx.x;       // b*S + s
    int b = row >> 10;
    int tid = threadIdx.x;
    int lane = tid & 63, wv = tid >> 6;
    int quad = lane >> 4, col = lane & 15;

    __shared__ __align__(16) unsigned short sB[HIDD][LSTR];   // [h][k]
    __shared__ __align__(16) unsigned short sA[TC][LSTR];     // [t_loc][k]
    __shared__ __align__(16) float sLog[SS];
    __shared__ float sZj[DD];
    __shared__ float sW2[HIDD];
    __shared__ float sRed[4];

    if (tid < DD) sZj[tid] = Zj[(size_t)row*DD + tid];
    __syncthreads();

    // B rows k: 0..23 = W1c (W1 rows 48..71), 24..47 = W1d (rows 72..95),
    //           48..71 = W1b (rows 24..47), 72 = tj+b1 (tj computed inline), 73..95 = 0
    for (int i = tid; i < 3*DD*HIDD; i += 256) {
        int part = i / (DD*HIDD); int r = i % (DD*HIDD);
        int d = r / HIDD, h2 = r % HIDD;
        int srow = (part == 0) ? (48 + d) : (part == 1) ? (72 + d) : (24 + d);
        sB[h2][part*DD + d] = f2bf(W1[srow*HIDD + h2]);
    }
    if (tid < HIDD) {
        float tj = b1[tid];
        #pragma unroll
        for (int d = 0; d < DD; ++d) tj = fmaf(sZj[d], W1[d*HIDD + tid], tj);
        sB[tid][72] = f2bf(tj);
        sW2[tid] = W2[tid];
    }
    for (int i = tid; i < HIDD*23; i += 256) {
        int h2 = i / 23, k = 73 + i % 23;
        sB[h2][k] = 0;
    }
    __syncthreads();

    short8 bfr[6][3];
    #pragma unroll
    for (int nf = 0; nf < 6; ++nf)
        #pragma unroll
        for (int ks = 0; ks < 3; ++ks)
            bfr[nf][ks] = *(const short8*)&sB[nf*16 + col][ks*32 + quad*8];
    float w2r[6];
    #pragma unroll
    for (int nf = 0; nf < 6; ++nf) w2r[nf] = sW2[col + nf*16];

    int t_loc = tid >> 1, hh = tid & 1;
    for (int chunk = 0; chunk < SS/TC; ++chunk) {
        {
            int t = chunk*TC + t_loc;
            const float4* zr = (const float4*)(Zi + ((size_t)((b<<10) + t))*DD);
            float4 z4[6];
            #pragma unroll
            for (int i = 0; i < 6; ++i) z4[i] = zr[i];
            float z[24];
            #pragma unroll
            for (int i = 0; i < 6; ++i) {
                z[4*i+0] = z4[i].x; z[4*i+1] = z4[i].y;
                z[4*i+2] = z4[i].z; z[4*i+3] = z4[i].w;
            }
            if (hh == 0) {
                #pragma unroll
                for (int g = 0; g < 3; ++g) {
                    uint4 w;
                    w.x = pack2(sZj[8*g+0]*z[8*g+0], sZj[8*g+1]*z[8*g+1]);
                    w.y = pack2(sZj[8*g+2]*z[8*g+2], sZj[8*g+3]*z[8*g+3]);
                    w.z = pack2(sZj[8*g+4]*z[8*g+4], sZj[8*g+5]*z[8*g+5]);
                    w.w = pack2(sZj[8*g+6]*z[8*g+6], sZj[8*g+7]*z[8*g+7]);
                    *(uint4*)&sA[t_loc][8*g] = w;
                }
                #pragma unroll
                for (int g = 0; g < 3; ++g) {
                    uint4 w;
                    w.x = pack2(fabsf(sZj[8*g+0]-z[8*g+0]), fabsf(sZj[8*g+1]-z[8*g+1]));
                    w.y = pack2(fabsf(sZj[8*g+2]-z[8*g+2]), fabsf(sZj[8*g+3]-z[8*g+3]));
                    w.z = pack2(fabsf(sZj[8*g+4]-z[8*g+4]), fabsf(sZj[8*g+5]-z[8*g+5]));
                    w.w = pack2(fabsf(sZj[8*g+6]-z[8*g+6]), fabsf(sZj[8*g+7]-z[8*g+7]));
                    *(uint4*)&sA[t_loc][24 + 8*g] = w;
                }
            } else {
                #pragma unroll
                for (int g = 0; g < 3; ++g) {
                    uint4 w;
                    w.x = pack2(z[8*g+0], z[8*g+1]);
                    w.y = pack2(z[8*g+2], z[8*g+3]);
                    w.z = pack2(z[8*g+4], z[8*g+5]);
                    w.w = pack2(z[8*g+6], z[8*g+7]);
                    *(uint4*)&sA[t_loc][48 + 8*g] = w;
                }
                uint4 w0; w0.x = pack2(1.0f, 0.0f); w0.y = 0; w0.z = 0; w0.w = 0;
                *(uint4*)&sA[t_loc][72] = w0;
                uint4 zz; zz.x = 0; zz.y = 0; zz.z = 0; zz.w = 0;
                *(uint4*)&sA[t_loc][80] = zz;
                *(uint4*)&sA[t_loc][88] = zz;
            }
        }
        __syncthreads();

        #pragma unroll
        for (int mt = 0; mt < 2; ++mt) {
            int arow = (wv*2 + mt)*16 + col;
            short8 a0 = *(const short8*)&sA[arow][quad*8];
            short8 a1 = *(const short8*)&sA[arow][32 + quad*8];
            short8 a2 = *(const short8*)&sA[arow][64 + quad*8];
            float s0 = 0.f, s1 = 0.f, s2 = 0.f, s3 = 0.f;
            #pragma unroll
            for (int nf = 0; nf < 6; ++nf) {
                floatx4 acc = {0.f, 0.f, 0.f, 0.f};
                acc = __builtin_amdgcn_mfma_f32_16x16x32_bf16(a0, bfr[nf][0], acc, 0, 0, 0);
                acc = __builtin_amdgcn_mfma_f32_16x16x32_bf16(a1, bfr[nf][1], acc, 0, 0, 0);
                acc = __builtin_amdgcn_mfma_f32_16x16x32_bf16(a2, bfr[nf][2], acc, 0, 0, 0);
                float w2v = w2r[nf];
                s0 = fmaf(fmaxf(acc[0], 0.f), w2v, s0);
                s1 = fmaf(fmaxf(acc[1], 0.f), w2v, s1);
                s2 = fmaf(fmaxf(acc[2], 0.f), w2v, s2);
                s3 = fmaf(fmaxf(acc[3], 0.f), w2v, s3);
            }
            #pragma unroll
            for (int m = 1; m < 16; m <<= 1) {
                s0 += __shfl_xor(s0, m, 64);
                s1 += __shfl_xor(s1, m, 64);
                s2 += __shfl_xor(s2, m, 64);
                s3 += __shfl_xor(s3, m, 64);
            }
            if (col == 0) {
                float4 o; o.x = s0; o.y = s1; o.z = s2; o.w = s3;
                *(float4*)&sLog[chunk*TC + (wv*2 + mt)*16 + quad*4] = o;
            }
        }
        __syncthreads();
    }

    // ---- softmax ----
    float lv[4];
    #pragma unroll
    for (int i = 0; i < 4; ++i) {
        int t = tid + i*256;
        lv[i] = sLog[t] + (1.0f - mask[(size_t)(b<<10) + t]) * (-3.402823466e+38f);
    }
    float m = fmaxf(fmaxf(lv[0], lv[1]), fmaxf(lv[2], lv[3]));
    #pragma unroll
    for (int off = 32; off; off >>= 1) m = fmaxf(m, __shfl_down(m, off, 64));
    if (lane == 0) sRed[wv] = m;
    __syncthreads();
    float M = fmaxf(fmaxf(sRed[0], sRed[1]), fmaxf(sRed[2], sRed[3]));
    float e[4]; float ssum = 0.f;
    #pragma unroll
    for (int i = 0; i < 4; ++i) { e[i] = expf(lv[i] - M); ssum += e[i]; }
    #pragma unroll
    for (int off = 32; off; off >>= 1) ssum += __shfl_down(ssum, off, 64);
    __syncthreads();
    if (lane == 0) sRed[wv] = ssum;
    __syncthreads();
    float inv = 1.0f / (sRed[0] + sRed[1] + sRed[2] + sRed[3]);
    #pragma unroll
    for (int i = 0; i < 4; ++i)
        probs[(size_t)row*SS + tid + i*256] = f2bf(e[i] * inv);
}

// ---------------- Kernel 3: bf16 MFMA GEMM, 128Mx64N tile, BK=64 -----------
// A: [rows][K] bf16 row-major.  BT: [N][K] bf16 (B transposed, K-major).
// MODE 0: ctx -> msgin builder (writes ctx | hj | ctx*hj, bf16)
// MODE 1: Y1 = bf16(relu(A@B + bias))
// MODE 2: out = f32(alpha*(A@B + bias))
template<int MODE>
__global__ __launch_bounds__(256) void k_mgemm(
    const unsigned short* __restrict__ A,
    const unsigned short* __restrict__ BT,
    const float* __restrict__ bias,
    const float* __restrict__ Hj,
    void* __restrict__ Cout,
    int K, const float* __restrict__ alpha_p)
{
    __shared__ __align__(16) unsigned short sA[128][72];
    __shared__ __align__(16) unsigned short sBT[64][72];
    int tid = threadIdx.x;
    int w = tid >> 6, lane = tid & 63;
    int quad = lane >> 4, col = lane & 15;

    int rows_per_batch = gridDim.y * 128;
    size_t aoff  = (size_t)blockIdx.z * rows_per_batch * K;
    size_t btoff = (size_t)blockIdx.z * 768 * K;
    A  += aoff;
    BT += btoff;
    int m0 = blockIdx.y * 128;
    int n0 = blockIdx.x * 64;
    size_t grow0 = (size_t)blockIdx.z * rows_per_batch + m0;

    floatx4 acc[2][4];
    #pragma unroll
    for (int mt = 0; mt < 2; ++mt)
        #pragma unroll
        for (int nt = 0; nt < 4; ++nt)
            acc[mt][nt] = (floatx4){0.f, 0.f, 0.f, 0.f};

    for (int kb = 0; kb < K; kb += 64) {
        #pragma unroll
        for (int i = 0; i < 4; ++i) {
            int c = tid + i*256;
            int row = c >> 3, kc = c & 7;
            *(uint4*)&sA[row][kc*8] =
                *(const uint4*)(A + (size_t)(m0 + row)*K + kb + kc*8);
        }
        #pragma unroll
        for (int i = 0; i < 2; ++i) {
            int c = tid + i*256;
            int row = c >> 3, kc = c & 7;
            *(uint4*)&sBT[row][kc*8] =
                *(const uint4*)(BT + (size_t)(n0 + row)*K + kb + kc*8);
        }
        __syncthreads();
        #pragma unroll
        for (int kt = 0; kt < 2; ++kt) {
            short8 av[2], bv[4];
            #pragma unroll
            for (int mt = 0; mt < 2; ++mt)
                av[mt] = *(const short8*)&sA[w*32 + mt*16 + col][kt*32 + quad*8];
            #pragma unroll
            for (int nt = 0; nt < 4; ++nt)
                bv[nt] = *(const short8*)&sBT[nt*16 + col][kt*32 + quad*8];
            #pragma unroll
            for (int mt = 0; mt < 2; ++mt)
                #pragma unroll
                for (int nt = 0; nt < 4; ++nt)
                    acc[mt][nt] = __builtin_amdgcn_mfma_f32_16x16x32_bf16(
                        av[mt], bv[nt], acc[mt][nt], 0, 0, 0);
        }
        __syncthreads();
    }

    float alpha = (MODE == 2) ? alpha_p[0] : 1.0f;
    #pragma unroll
    for (int mt = 0; mt < 2; ++mt) {
        #pragma unroll
        for (int nt = 0; nt < 4; ++nt) {
            int n = n0 + nt*16 + col;
            #pragma unroll
            for (int r = 0; r < 4; ++r) {
                int m = w*32 + mt*16 + quad*4 + r;
                size_t g = grow0 + m;
                float v = acc[mt][nt][r];
                if (MODE == 0) {
                    float hj = Hj[g*HH + n];
                    unsigned short* msgin = (unsigned short*)Cout;
                    msgin[g*VINN + n]        = f2bf(v);
                    msgin[g*VINN + HH + n]   = f2bf(hj);
                    msgin[g*VINN + 2*HH + n] = f2bf(v*hj);
                } else if (MODE == 1) {
                    ((unsigned short*)Cout)[g*VHIDD + n] =
                        f2bf(fmaxf(v + bias[n], 0.f));
                } else {
                    ((float*)Cout)[g*HH + n] = alpha*(v + bias[n]);
                }
            }
        }
    }
}

extern "C" void kernel_launch(void* const* d_in, const int* in_sizes, int n_in,
                              void* d_out, int out_size, void* d_ws, size_t ws_size,
                              hipStream_t stream)
{
    const float* Hj   = (const float*)d_in[0];
    const float* Hi   = (const float*)d_in[1];
    const float* mask = (const float*)d_in[2];
    const float* Wpj  = (const float*)d_in[3];
    const float* Wpi  = (const float*)d_in[4];
    const float* W1   = (const float*)d_in[5];
    const float* b1   = (const float*)d_in[6];
    const float* W2   = (const float*)d_in[7];
    const float* Wv1  = (const float*)d_in[9];
    const float* bv1  = (const float*)d_in[10];
    const float* Wv2  = (const float*)d_in[11];
    const float* bv2  = (const float*)d_in[12];
    const float* alpha = (const float*)d_in[13];
    float* out = (float*)d_out;

    const int NR = BB*SS;                 // 2048
    char* p = (char*)d_ws;
    auto alloc = [&](size_t bytes) {
        char* r = p; p += (bytes + 255) & ~(size_t)255; return r;
    };
    float* Zj             = (float*)alloc((size_t)NR*DD*4);
    float* Zi             = (float*)alloc((size_t)NR*DD*4);
    unsigned short* probsb = (unsigned short*)alloc((size_t)NR*SS*2);
    unsigned short* HiT    = (unsigned short*)alloc((size_t)BB*HH*SS*2);
    unsigned short* Wv1T   = (unsigned short*)alloc((size_t)VHIDD*VINN*2);
    unsigned short* Wv2T   = (unsigned short*)alloc((size_t)HH*VHIDD*2);
    unsigned short* msginb = (unsigned short*)alloc((size_t)NR*VINN*2);
    unsigned short* Y1b    = (unsigned short*)alloc((size_t)NR*VHIDD*2);

    k_tconv<<<dim3(VHIDD/32, VINN/32, 1), 256, 0, stream>>>(Wv1, Wv1T, VINN, VHIDD);
    k_tconv<<<dim3(HH/32, VHIDD/32, 1), 256, 0, stream>>>(Wv2, Wv2T, VHIDD, HH);
    k_tconv<<<dim3(HH/32, SS/32, BB), 256, 0, stream>>>(Hi, HiT, SS, HH);
    k_zproj<<<2*NR/64, 256, 0, stream>>>(Hj, Hi, Wpj, Wpi, Zj, Zi);
    k_attn<<<NR, 256, 0, stream>>>(Zj, Zi, W1, b1, W2, mask, probsb);
    // ctx GEMM: per b, M=1024 (s), N=768 (h), K=1024 (t)
    k_mgemm<0><<<dim3(HH/64, SS/128, BB), 256, 0, stream>>>(
        probsb, HiT, nullptr, Hj, msginb, SS, alpha);
    // MLP GEMM1: M=2048, N=768, K=2304
    k_mgemm<1><<<dim3(VHIDD/64, NR/128, 1), 256, 0, stream>>>(
        msginb, Wv1T, bv1, nullptr, Y1b, VINN, alpha);
    // MLP GEMM2: M=2048, N=768, K=768
    k_mgemm<2><<<dim3(HH/64, NR/128, 1), 256, 0, stream>>>(
        Y1b, Wv2T, bv2, nullptr, out, VHIDD, alpha);
}

// Round 5
// 319.884 us; speedup vs baseline: 2.3816x; 1.1617x over previous
//
#include <hip/hip_runtime.h>
#include <math.h>

#define BB   2
#define SS   1024
#define HH   768
#define DD   24
#define HIDD 96
#define VINN 2304   // 3*H
#define VHIDD 768

typedef __attribute__((ext_vector_type(8))) short short8;
typedef __attribute__((ext_vector_type(4))) float floatx4;

static __device__ inline unsigned short f2bf(float x) {
    unsigned int u = __float_as_uint(x);
    u = (u + 0x7FFFu + ((u >> 16) & 1u)) >> 16;
    return (unsigned short)u;
}
static __device__ inline unsigned int pack2(float a, float b) {
    return (unsigned int)f2bf(a) | ((unsigned int)f2bf(b) << 16);
}

// ---------------- Kernel 0: f32 -> bf16 transpose-convert ------------------
__global__ __launch_bounds__(256) void k_tconv(
    const float* __restrict__ in, unsigned short* __restrict__ out,
    int R, int C)
{
    size_t zoff = (size_t)blockIdx.z * R * C;
    in += zoff; out += zoff;
    __shared__ float tile[32][33];
    int r0 = blockIdx.y * 32, c0 = blockIdx.x * 32;
    int tc = threadIdx.x & 31, tr = threadIdx.x >> 5;
    #pragma unroll
    for (int i = 0; i < 4; ++i)
        tile[tr + i*8][tc] = in[(size_t)(r0 + tr + i*8)*C + c0 + tc];
    __syncthreads();
    #pragma unroll
    for (int i = 0; i < 4; ++i)
        out[(size_t)(c0 + tr + i*8)*R + r0 + tc] = f2bf(tile[tc][tr + i*8]);
}

// ---------------- Kernel 1: Z projections via MFMA, packed-bf16 output -----
// Virtual M = 4096: rows 0..2047 -> Zj = Hj@Wpj, rows 2048..4095 -> Zi = Hi@Wpi.
// Output: packed bf16 pairs, [row][12] uints (24 bf16 per row).
__global__ __launch_bounds__(256) void k_zproj(
    const float* __restrict__ Hj, const float* __restrict__ Hi,
    const float* __restrict__ Wpj, const float* __restrict__ Wpi,
    unsigned* __restrict__ Zjp, unsigned* __restrict__ Zip)
{
    __shared__ __align__(16) unsigned short sA[64][72];
    __shared__ __align__(16) unsigned short sBT[32][72];
    int tid = threadIdx.x;
    int w = tid >> 6, lane = tid & 63;
    int quad = lane >> 4, col = lane & 15;

    int m0 = blockIdx.x * 64;
    bool isJ = (m0 < BB*SS);
    const float* src = isJ ? Hj : Hi;
    const float* Wp  = isJ ? Wpj : Wpi;
    unsigned* Zp     = isJ ? Zjp : Zip;
    int rowbase = isJ ? m0 : (m0 - BB*SS);

    floatx4 acc[2];
    acc[0] = (floatx4){0.f,0.f,0.f,0.f};
    acc[1] = (floatx4){0.f,0.f,0.f,0.f};

    for (int kb = 0; kb < HH; kb += 64) {
        #pragma unroll
        for (int i = 0; i < 4; ++i) {
            int f4 = tid + i*256;
            int r = f4 >> 4, c4 = f4 & 15;
            float4 v = *(const float4*)(src + (size_t)(rowbase + r)*HH + kb + c4*4);
            uint2 pkt; pkt.x = pack2(v.x, v.y); pkt.y = pack2(v.z, v.w);
            *(uint2*)&sA[r][c4*4] = pkt;
        }
        {
            const float* wsrc = Wp + (size_t)kb*DD;
            #pragma unroll
            for (int i = 0; i < 6; ++i) {
                int idx = tid + i*256;
                int k = idx / DD, n = idx % DD;
                sBT[n][k] = f2bf(wsrc[idx]);
            }
        }
        __syncthreads();
        #pragma unroll
        for (int kt = 0; kt < 2; ++kt) {
            short8 av = *(const short8*)&sA[w*16 + col][kt*32 + quad*8];
            #pragma unroll
            for (int nt = 0; nt < 2; ++nt) {
                short8 bv = *(const short8*)&sBT[nt*16 + col][kt*32 + quad*8];
                acc[nt] = __builtin_amdgcn_mfma_f32_16x16x32_bf16(av, bv, acc[nt], 0, 0, 0);
            }
        }
        __syncthreads();
    }
    #pragma unroll
    for (int nt = 0; nt < 2; ++nt) {
        #pragma unroll
        for (int r = 0; r < 4; ++r) {
            float v = acc[nt][r];
            float vn = __shfl_xor(v, 1, 64);
            int n = nt*16 + col;
            if (!(col & 1) && n < DD) {
                int m = w*16 + quad*4 + r;
                Zp[(size_t)(rowbase + m)*12 + (n >> 1)] = pack2(v, vn);
            }
        }
    }
}

// ---------------- Kernel 2: MFMA logits + softmax -> probs (bf16) ----------
// A[t, k]: k 0..23 = Zi (bf16), 24..47 = |Zj-Zi|, 48 = 1, 49..63 = 0.
// B[k, h]: k 0..23 = Zj[d]*W1c[d,h]+W1b[d,h], 24..47 = W1d, 48 = tj+b1, pad 0.
#define LSTR 72
#define TC 128
__global__ __launch_bounds__(256) void k_attn(
    const unsigned* __restrict__ Zjp, const unsigned* __restrict__ Zip,
    const float* __restrict__ W1, const float* __restrict__ b1,
    const float* __restrict__ W2,
    const float* __restrict__ mask, unsigned short* __restrict__ probs)
{
    int row = blockIdx.x;       // b*S + s
    int b = row >> 10;
    int tid = threadIdx.x;
    int lane = tid & 63, wv = tid >> 6;
    int quad = lane >> 4, col = lane & 15;

    __shared__ __align__(16) unsigned short sAB[128*LSTR];  // B-build, then A
    __shared__ __align__(16) float sLog[SS];
    __shared__ unsigned sZjp[12];
    __shared__ float sW2[HIDD];
    __shared__ float sRed[4];

    if (tid < 12) sZjp[tid] = Zjp[(size_t)row*12 + tid];
    if (tid < HIDD) sW2[tid] = W2[tid];
    __syncthreads();

    // ---- build B in sAB (rows h = 0..95, k = 0..63) ----
    if (tid < HIDD) {
        int h = tid;
        float zj[24];
        #pragma unroll
        for (int u = 0; u < 12; ++u) {
            unsigned z = sZjp[u];
            zj[2*u]   = __uint_as_float(z << 16);
            zj[2*u+1] = __uint_as_float(z & 0xffff0000u);
        }
        float tj = b1[h];
        #pragma unroll
        for (int d = 0; d < DD; ++d) tj = fmaf(zj[d], W1[d*HIDD + h], tj);
        unsigned short* rowp = &sAB[h*LSTR];
        #pragma unroll
        for (int d = 0; d < DD; ++d)
            rowp[d] = f2bf(fmaf(zj[d], W1[(48+d)*HIDD + h], W1[(24+d)*HIDD + h]));
        #pragma unroll
        for (int d = 0; d < DD; ++d)
            rowp[24+d] = f2bf(W1[(72+d)*HIDD + h]);
        rowp[48] = f2bf(tj);
        #pragma unroll
        for (int k = 49; k < 64; ++k) rowp[k] = 0;
    }
    __syncthreads();

    short8 bfr[6][2];
    #pragma unroll
    for (int nf = 0; nf < 6; ++nf)
        #pragma unroll
        for (int kt = 0; kt < 2; ++kt)
            bfr[nf][kt] = *(const short8*)&sAB[(nf*16 + col)*LSTR + kt*32 + quad*8];
    float w2r[6];
    #pragma unroll
    for (int nf = 0; nf < 6; ++nf) w2r[nf] = sW2[col + nf*16];
    __syncthreads();   // sAB now reused as A

    int t_loc = tid >> 1, hh = tid & 1;
    const unsigned* zbase = Zip + (size_t)(b << 10) * 12;
    for (int chunk = 0; chunk < SS/TC; ++chunk) {
        // ---- A-pack: 2 threads per t-row ----
        {
            int t = chunk*TC + t_loc;
            const unsigned* zr = zbase + (size_t)t*12;
            unsigned short* rowp = &sAB[t_loc*LSTR];
            uint4 first = *(const uint4*)(zr + hh*4);      // uints 0-3 | 4-7
            *(uint4*)&rowp[hh*8] = first;
            uint4 second;
            if (hh) second = *(const uint4*)(zr + 8);       // uints 8-11
            else  { second.x = 0x3F80u; second.y = 0; second.z = 0; second.w = 0; }
            *(uint4*)&rowp[hh ? 16 : 48] = second;
            if (!hh) { uint4 zz; zz.x=0; zz.y=0; zz.z=0; zz.w=0; *(uint4*)&rowp[56] = zz; }
            uint2 ext; ext.x = 0; ext.y = 0;
            if (!hh) ext = *(const uint2*)(zr + 4);         // uints 4-5
            unsigned myz[6];
            if (hh) { myz[0]=first.z; myz[1]=first.w; myz[2]=second.x;
                      myz[3]=second.y; myz[4]=second.z; myz[5]=second.w; }
            else    { myz[0]=first.x; myz[1]=first.y; myz[2]=first.z;
                      myz[3]=first.w; myz[4]=ext.x;   myz[5]=ext.y; }
            unsigned q[6];
            #pragma unroll
            for (int u = 0; u < 6; ++u) {
                unsigned za = sZjp[hh*6 + u], zb = myz[u];
                float alo = __uint_as_float(za << 16);
                float ahi = __uint_as_float(za & 0xffff0000u);
                float blo = __uint_as_float(zb << 16);
                float bhi = __uint_as_float(zb & 0xffff0000u);
                unsigned dlo = __float_as_uint(fabsf(alo - blo)) + 0x8000u;
                unsigned dhi = __float_as_uint(fabsf(ahi - bhi)) + 0x8000u;
                q[u] = __builtin_amdgcn_perm(dhi, dlo, 0x07060302u);
            }
            #pragma unroll
            for (int j = 0; j < 3; ++j) {
                uint2 wq; wq.x = q[2*j]; wq.y = q[2*j+1];
                *(uint2*)&rowp[24 + hh*12 + 4*j] = wq;
            }
        }
        __syncthreads();

        // ---- MFMA + relu-dot-W2 + col reduce ----
        #pragma unroll
        for (int mt = 0; mt < 2; ++mt) {
            int arow = (wv*2 + mt)*16 + col;
            const unsigned short* ar = &sAB[arow*LSTR];
            short8 a0 = *(const short8*)&ar[quad*8];
            short8 a1 = *(const short8*)&ar[32 + quad*8];
            float s0 = 0.f, s1 = 0.f, s2 = 0.f, s3 = 0.f;
            #pragma unroll
            for (int nf = 0; nf < 6; ++nf) {
                floatx4 acc = {0.f, 0.f, 0.f, 0.f};
                acc = __builtin_amdgcn_mfma_f32_16x16x32_bf16(a0, bfr[nf][0], acc, 0, 0, 0);
                acc = __builtin_amdgcn_mfma_f32_16x16x32_bf16(a1, bfr[nf][1], acc, 0, 0, 0);
                float w2v = w2r[nf];
                s0 = fmaf(fmaxf(acc[0], 0.f), w2v, s0);
                s1 = fmaf(fmaxf(acc[1], 0.f), w2v, s1);
                s2 = fmaf(fmaxf(acc[2], 0.f), w2v, s2);
                s3 = fmaf(fmaxf(acc[3], 0.f), w2v, s3);
            }
            #pragma unroll
            for (int m = 1; m < 16; m <<= 1) {
                s0 += __shfl_xor(s0, m, 64);
                s1 += __shfl_xor(s1, m, 64);
                s2 += __shfl_xor(s2, m, 64);
                s3 += __shfl_xor(s3, m, 64);
            }
            if (col == 0) {
                float4 o; o.x = s0; o.y = s1; o.z = s2; o.w = s3;
                *(float4*)&sLog[chunk*TC + (wv*2 + mt)*16 + quad*4] = o;
            }
        }
        __syncthreads();
    }

    // ---- softmax ----
    float lv[4];
    #pragma unroll
    for (int i = 0; i < 4; ++i) {
        int t = tid + i*256;
        lv[i] = sLog[t] + (1.0f - mask[(size_t)(b<<10) + t]) * (-3.402823466e+38f);
    }
    float m = fmaxf(fmaxf(lv[0], lv[1]), fmaxf(lv[2], lv[3]));
    #pragma unroll
    for (int off = 32; off; off >>= 1) m = fmaxf(m, __shfl_down(m, off, 64));
    if (lane == 0) sRed[wv] = m;
    __syncthreads();
    float M = fmaxf(fmaxf(sRed[0], sRed[1]), fmaxf(sRed[2], sRed[3]));
    float e[4]; float ssum = 0.f;
    #pragma unroll
    for (int i = 0; i < 4; ++i) { e[i] = expf(lv[i] - M); ssum += e[i]; }
    #pragma unroll
    for (int off = 32; off; off >>= 1) ssum += __shfl_down(ssum, off, 64);
    __syncthreads();
    if (lane == 0) sRed[wv] = ssum;
    __syncthreads();
    float inv = 1.0f / (sRed[0] + sRed[1] + sRed[2] + sRed[3]);
    #pragma unroll
    for (int i = 0; i < 4; ++i)
        probs[(size_t)row*SS + tid + i*256] = f2bf(e[i] * inv);
}

// ---------------- Kernel 3: bf16 MFMA GEMM, 64x64 tile, double-buffered ----
// A: [rows][K] bf16 row-major.  BT: [N][K] bf16 (K-major).
// MODE 0: msgin builder   MODE 1: relu(A@B+bias) bf16   MODE 2: alpha*(A@B+bias) f32
template<int MODE>
__global__ __launch_bounds__(256) void k_mgemm(
    const unsigned short* __restrict__ A,
    const unsigned short* __restrict__ BT,
    const float* __restrict__ bias,
    const float* __restrict__ Hj,
    void* __restrict__ Cout,
    int K, const float* __restrict__ alpha_p)
{
    __shared__ __align__(16) unsigned short sA[2][64][72];
    __shared__ __align__(16) unsigned short sB[2][64][72];
    int tid = threadIdx.x;
    int w = tid >> 6, lane = tid & 63;
    int quad = lane >> 4, col = lane & 15;

    int rows_per_batch = gridDim.y * 64;
    A  += (size_t)blockIdx.z * rows_per_batch * K;
    BT += (size_t)blockIdx.z * 768 * K;
    int m0 = blockIdx.y * 64, n0 = blockIdx.x * 64;
    size_t grow0 = (size_t)blockIdx.z * rows_per_batch + m0;

    floatx4 acc[4];
    #pragma unroll
    for (int nt = 0; nt < 4; ++nt) acc[nt] = (floatx4){0.f,0.f,0.f,0.f};

    uint4 pa[2], pb[2];
    #pragma unroll
    for (int i = 0; i < 2; ++i) {
        int idx = tid + i*256, r = idx >> 3, kc = idx & 7;
        pa[i] = *(const uint4*)(A  + (size_t)(m0 + r)*K + kc*8);
        pb[i] = *(const uint4*)(BT + (size_t)(n0 + r)*K + kc*8);
    }
    #pragma unroll
    for (int i = 0; i < 2; ++i) {
        int idx = tid + i*256, r = idx >> 3, kc = idx & 7;
        *(uint4*)&sA[0][r][kc*8] = pa[i];
        *(uint4*)&sB[0][r][kc*8] = pb[i];
    }
    __syncthreads();

    int nk = K >> 6;
    for (int kb = 0; kb < nk; ++kb) {
        int cur = kb & 1;
        bool more = (kb + 1 < nk);
        if (more) {
            #pragma unroll
            for (int i = 0; i < 2; ++i) {
                int idx = tid + i*256, r = idx >> 3, kc = idx & 7;
                pa[i] = *(const uint4*)(A  + (size_t)(m0 + r)*K + (kb+1)*64 + kc*8);
                pb[i] = *(const uint4*)(BT + (size_t)(n0 + r)*K + (kb+1)*64 + kc*8);
            }
        }
        #pragma unroll
        for (int kt = 0; kt < 2; ++kt) {
            short8 av = *(const short8*)&sA[cur][w*16 + col][kt*32 + quad*8];
            #pragma unroll
            for (int nt = 0; nt < 4; ++nt) {
                short8 bv = *(const short8*)&sB[cur][nt*16 + col][kt*32 + quad*8];
                acc[nt] = __builtin_amdgcn_mfma_f32_16x16x32_bf16(av, bv, acc[nt], 0, 0, 0);
            }
        }
        if (more) {
            #pragma unroll
            for (int i = 0; i < 2; ++i) {
                int idx = tid + i*256, r = idx >> 3, kc = idx & 7;
                *(uint4*)&sA[cur^1][r][kc*8] = pa[i];
                *(uint4*)&sB[cur^1][r][kc*8] = pb[i];
            }
        }
        __syncthreads();
    }

    float alpha = (MODE == 2) ? alpha_p[0] : 1.0f;
    #pragma unroll
    for (int nt = 0; nt < 4; ++nt) {
        int n = n0 + nt*16 + col;
        #pragma unroll
        for (int r = 0; r < 4; ++r) {
            int m = w*16 + quad*4 + r;
            size_t g = grow0 + m;
            float v = acc[nt][r];
            if (MODE == 0) {
                float hj = Hj[g*HH + n];
                unsigned short* msgin = (unsigned short*)Cout;
                msgin[g*VINN + n]        = f2bf(v);
                msgin[g*VINN + HH + n]   = f2bf(hj);
                msgin[g*VINN + 2*HH + n] = f2bf(v*hj);
            } else if (MODE == 1) {
                ((unsigned short*)Cout)[g*VHIDD + n] = f2bf(fmaxf(v + bias[n], 0.f));
            } else {
                ((float*)Cout)[g*HH + n] = alpha*(v + bias[n]);
            }
        }
    }
}

extern "C" void kernel_launch(void* const* d_in, const int* in_sizes, int n_in,
                              void* d_out, int out_size, void* d_ws, size_t ws_size,
                              hipStream_t stream)
{
    const float* Hj   = (const float*)d_in[0];
    const float* Hi   = (const float*)d_in[1];
    const float* mask = (const float*)d_in[2];
    const float* Wpj  = (const float*)d_in[3];
    const float* Wpi  = (const float*)d_in[4];
    const float* W1   = (const float*)d_in[5];
    const float* b1   = (const float*)d_in[6];
    const float* W2   = (const float*)d_in[7];
    const float* Wv1  = (const float*)d_in[9];
    const float* bv1  = (const float*)d_in[10];
    const float* Wv2  = (const float*)d_in[11];
    const float* bv2  = (const float*)d_in[12];
    const float* alpha = (const float*)d_in[13];
    float* out = (float*)d_out;

    const int NR = BB*SS;                 // 2048
    char* p = (char*)d_ws;
    auto alloc = [&](size_t bytes) {
        char* r = p; p += (bytes + 255) & ~(size_t)255; return r;
    };
    unsigned* Zjp          = (unsigned*)alloc((size_t)NR*12*4);
    unsigned* Zip          = (unsigned*)alloc((size_t)NR*12*4);
    unsigned short* probsb = (unsigned short*)alloc((size_t)NR*SS*2);
    unsigned short* HiT    = (unsigned short*)alloc((size_t)BB*HH*SS*2);
    unsigned short* Wv1T   = (unsigned short*)alloc((size_t)VHIDD*VINN*2);
    unsigned short* Wv2T   = (unsigned short*)alloc((size_t)HH*VHIDD*2);
    unsigned short* msginb = (unsigned short*)alloc((size_t)NR*VINN*2);
    unsigned short* Y1b    = (unsigned short*)alloc((size_t)NR*VHIDD*2);

    k_tconv<<<dim3(VHIDD/32, VINN/32, 1), 256, 0, stream>>>(Wv1, Wv1T, VINN, VHIDD);
    k_tconv<<<dim3(HH/32, VHIDD/32, 1), 256, 0, stream>>>(Wv2, Wv2T, VHIDD, HH);
    k_tconv<<<dim3(HH/32, SS/32, BB), 256, 0, stream>>>(Hi, HiT, SS, HH);
    k_zproj<<<2*NR/64, 256, 0, stream>>>(Hj, Hi, Wpj, Wpi, Zjp, Zip);
    k_attn<<<NR, 256, 0, stream>>>(Zjp, Zip, W1, b1, W2, mask, probsb);
    // ctx GEMM: per b, M=1024 (s), N=768 (h), K=1024 (t)
    k_mgemm<0><<<dim3(HH/64, SS/64, BB), 256, 0, stream>>>(
        probsb, HiT, nullptr, Hj, msginb, SS, alpha);
    // MLP GEMM1: M=2048, N=768, K=2304
    k_mgemm<1><<<dim3(VHIDD/64, NR/64, 1), 256, 0, stream>>>(
        msginb, Wv1T, bv1, nullptr, Y1b, VINN, alpha);
    // MLP GEMM2: M=2048, N=768, K=768
    k_mgemm<2><<<dim3(HH/64, NR/64, 1), 256, 0, stream>>>(
        Y1b, Wv2T, bv2, nullptr, out, VHIDD, alpha);
}

// Round 6
// 316.416 us; speedup vs baseline: 2.4077x; 1.0110x over previous
//
#include <hip/hip_runtime.h>
#include <math.h>

#define BB   2
#define SS   1024
#define HH   768
#define DD   24
#define HIDD 96
#define VINN 2304   // 3*H
#define VHIDD 768
#define NRR  2048   // BB*SS

typedef __attribute__((ext_vector_type(8))) short short8;
typedef __attribute__((ext_vector_type(4))) float floatx4;

static __device__ inline unsigned short f2bf(float x) {
    unsigned int u = __float_as_uint(x);
    u = (u + 0x7FFFu + ((u >> 16) & 1u)) >> 16;
    return (unsigned short)u;
}
static __device__ inline unsigned int pack2(float a, float b) {
    return (unsigned int)f2bf(a) | ((unsigned int)f2bf(b) << 16);
}

// ---------------- Kernel 0: f32 -> bf16 transpose-convert ------------------
__global__ __launch_bounds__(256) void k_tconv(
    const float* __restrict__ in, unsigned short* __restrict__ out,
    int R, int C)
{
    size_t zoff = (size_t)blockIdx.z * R * C;
    in += zoff; out += zoff;
    __shared__ float tile[32][33];
    int r0 = blockIdx.y * 32, c0 = blockIdx.x * 32;
    int tc = threadIdx.x & 31, tr = threadIdx.x >> 5;
    #pragma unroll
    for (int i = 0; i < 4; ++i)
        tile[tr + i*8][tc] = in[(size_t)(r0 + tr + i*8)*C + c0 + tc];
    __syncthreads();
    #pragma unroll
    for (int i = 0; i < 4; ++i)
        out[(size_t)(c0 + tr + i*8)*R + r0 + tc] = f2bf(tile[tc][tr + i*8]);
}

// ---------------- Kernel 1: Z projections via MFMA, packed-bf16 output -----
__global__ __launch_bounds__(256) void k_zproj(
    const float* __restrict__ Hj, const float* __restrict__ Hi,
    const float* __restrict__ Wpj, const float* __restrict__ Wpi,
    unsigned* __restrict__ Zjp, unsigned* __restrict__ Zip)
{
    __shared__ __align__(16) unsigned short sA[64][72];
    __shared__ __align__(16) unsigned short sBT[32][72];
    int tid = threadIdx.x;
    int w = tid >> 6, lane = tid & 63;
    int quad = lane >> 4, col = lane & 15;

    int m0 = blockIdx.x * 64;
    bool isJ = (m0 < NRR);
    const float* src = isJ ? Hj : Hi;
    const float* Wp  = isJ ? Wpj : Wpi;
    unsigned* Zp     = isJ ? Zjp : Zip;
    int rowbase = isJ ? m0 : (m0 - NRR);

    floatx4 acc[2];
    acc[0] = (floatx4){0.f,0.f,0.f,0.f};
    acc[1] = (floatx4){0.f,0.f,0.f,0.f};

    for (int kb = 0; kb < HH; kb += 64) {
        #pragma unroll
        for (int i = 0; i < 4; ++i) {
            int f4 = tid + i*256;
            int r = f4 >> 4, c4 = f4 & 15;
            float4 v = *(const float4*)(src + (size_t)(rowbase + r)*HH + kb + c4*4);
            uint2 pkt; pkt.x = pack2(v.x, v.y); pkt.y = pack2(v.z, v.w);
            *(uint2*)&sA[r][c4*4] = pkt;
        }
        {
            const float* wsrc = Wp + (size_t)kb*DD;
            #pragma unroll
            for (int i = 0; i < 6; ++i) {
                int idx = tid + i*256;
                int k = idx / DD, n = idx % DD;
                sBT[n][k] = f2bf(wsrc[idx]);
            }
        }
        __syncthreads();
        #pragma unroll
        for (int kt = 0; kt < 2; ++kt) {
            short8 av = *(const short8*)&sA[w*16 + col][kt*32 + quad*8];
            #pragma unroll
            for (int nt = 0; nt < 2; ++nt) {
                short8 bv = *(const short8*)&sBT[nt*16 + col][kt*32 + quad*8];
                acc[nt] = __builtin_amdgcn_mfma_f32_16x16x32_bf16(av, bv, acc[nt], 0, 0, 0);
            }
        }
        __syncthreads();
    }
    #pragma unroll
    for (int nt = 0; nt < 2; ++nt) {
        #pragma unroll
        for (int r = 0; r < 4; ++r) {
            float v = acc[nt][r];
            float vn = __shfl_xor(v, 1, 64);
            int n = nt*16 + col;
            if (!(col & 1) && n < DD) {
                int m = w*16 + quad*4 + r;
                Zp[(size_t)(rowbase + m)*12 + (n >> 1)] = pack2(v, vn);
            }
        }
    }
}

// ---------------- Kernel 2: MFMA logits + softmax -> probs (bf16) ----------
#define LSTR 72
#define TC 128
__global__ __launch_bounds__(256) void k_attn(
    const unsigned* __restrict__ Zjp, const unsigned* __restrict__ Zip,
    const float* __restrict__ W1, const float* __restrict__ b1,
    const float* __restrict__ W2,
    const float* __restrict__ mask, unsigned short* __restrict__ probs)
{
    int row = blockIdx.x;       // b*S + s
    int b = row >> 10;
    int tid = threadIdx.x;
    int lane = tid & 63, wv = tid >> 6;
    int quad = lane >> 4, col = lane & 15;

    __shared__ __align__(16) unsigned short sAB[128*LSTR];  // B-build, then A
    __shared__ __align__(16) float sLog[SS];
    __shared__ unsigned sZjp[12];
    __shared__ float sW2[HIDD];
    __shared__ float sRed[4];

    if (tid < 12) sZjp[tid] = Zjp[(size_t)row*12 + tid];
    if (tid < HIDD) sW2[tid] = W2[tid];
    __syncthreads();

    if (tid < HIDD) {
        int h = tid;
        float zj[24];
        #pragma unroll
        for (int u = 0; u < 12; ++u) {
            unsigned z = sZjp[u];
            zj[2*u]   = __uint_as_float(z << 16);
            zj[2*u+1] = __uint_as_float(z & 0xffff0000u);
        }
        float tj = b1[h];
        #pragma unroll
        for (int d = 0; d < DD; ++d) tj = fmaf(zj[d], W1[d*HIDD + h], tj);
        unsigned short* rowp = &sAB[h*LSTR];
        #pragma unroll
        for (int d = 0; d < DD; ++d)
            rowp[d] = f2bf(fmaf(zj[d], W1[(48+d)*HIDD + h], W1[(24+d)*HIDD + h]));
        #pragma unroll
        for (int d = 0; d < DD; ++d)
            rowp[24+d] = f2bf(W1[(72+d)*HIDD + h]);
        rowp[48] = f2bf(tj);
        #pragma unroll
        for (int k = 49; k < 64; ++k) rowp[k] = 0;
    }
    __syncthreads();

    short8 bfr[6][2];
    #pragma unroll
    for (int nf = 0; nf < 6; ++nf)
        #pragma unroll
        for (int kt = 0; kt < 2; ++kt)
            bfr[nf][kt] = *(const short8*)&sAB[(nf*16 + col)*LSTR + kt*32 + quad*8];
    float w2r[6];
    #pragma unroll
    for (int nf = 0; nf < 6; ++nf) w2r[nf] = sW2[col + nf*16];
    __syncthreads();   // sAB now reused as A

    int t_loc = tid >> 1, hh = tid & 1;
    const unsigned* zbase = Zip + (size_t)(b << 10) * 12;
    for (int chunk = 0; chunk < SS/TC; ++chunk) {
        {
            int t = chunk*TC + t_loc;
            const unsigned* zr = zbase + (size_t)t*12;
            unsigned short* rowp = &sAB[t_loc*LSTR];
            uint4 first = *(const uint4*)(zr + hh*4);
            *(uint4*)&rowp[hh*8] = first;
            uint4 second;
            if (hh) second = *(const uint4*)(zr + 8);
            else  { second.x = 0x3F80u; second.y = 0; second.z = 0; second.w = 0; }
            *(uint4*)&rowp[hh ? 16 : 48] = second;
            if (!hh) { uint4 zz; zz.x=0; zz.y=0; zz.z=0; zz.w=0; *(uint4*)&rowp[56] = zz; }
            uint2 ext; ext.x = 0; ext.y = 0;
            if (!hh) ext = *(const uint2*)(zr + 4);
            unsigned myz[6];
            if (hh) { myz[0]=first.z; myz[1]=first.w; myz[2]=second.x;
                      myz[3]=second.y; myz[4]=second.z; myz[5]=second.w; }
            else    { myz[0]=first.x; myz[1]=first.y; myz[2]=first.z;
                      myz[3]=first.w; myz[4]=ext.x;   myz[5]=ext.y; }
            unsigned q[6];
            #pragma unroll
            for (int u = 0; u < 6; ++u) {
                unsigned za = sZjp[hh*6 + u], zb = myz[u];
                float alo = __uint_as_float(za << 16);
                float ahi = __uint_as_float(za & 0xffff0000u);
                float blo = __uint_as_float(zb << 16);
                float bhi = __uint_as_float(zb & 0xffff0000u);
                unsigned dlo = __float_as_uint(fabsf(alo - blo)) + 0x8000u;
                unsigned dhi = __float_as_uint(fabsf(ahi - bhi)) + 0x8000u;
                q[u] = __builtin_amdgcn_perm(dhi, dlo, 0x07060302u);
            }
            #pragma unroll
            for (int j = 0; j < 3; ++j) {
                uint2 wq; wq.x = q[2*j]; wq.y = q[2*j+1];
                *(uint2*)&rowp[24 + hh*12 + 4*j] = wq;
            }
        }
        __syncthreads();

        #pragma unroll
        for (int mt = 0; mt < 2; ++mt) {
            int arow = (wv*2 + mt)*16 + col;
            const unsigned short* ar = &sAB[arow*LSTR];
            short8 a0 = *(const short8*)&ar[quad*8];
            short8 a1 = *(const short8*)&ar[32 + quad*8];
            float s0 = 0.f, s1 = 0.f, s2 = 0.f, s3 = 0.f;
            #pragma unroll
            for (int nf = 0; nf < 6; ++nf) {
                floatx4 acc = {0.f, 0.f, 0.f, 0.f};
                acc = __builtin_amdgcn_mfma_f32_16x16x32_bf16(a0, bfr[nf][0], acc, 0, 0, 0);
                acc = __builtin_amdgcn_mfma_f32_16x16x32_bf16(a1, bfr[nf][1], acc, 0, 0, 0);
                float w2v = w2r[nf];
                s0 = fmaf(fmaxf(acc[0], 0.f), w2v, s0);
                s1 = fmaf(fmaxf(acc[1], 0.f), w2v, s1);
                s2 = fmaf(fmaxf(acc[2], 0.f), w2v, s2);
                s3 = fmaf(fmaxf(acc[3], 0.f), w2v, s3);
            }
            #pragma unroll
            for (int m = 1; m < 16; m <<= 1) {
                s0 += __shfl_xor(s0, m, 64);
                s1 += __shfl_xor(s1, m, 64);
                s2 += __shfl_xor(s2, m, 64);
                s3 += __shfl_xor(s3, m, 64);
            }
            if (col == 0) {
                float4 o; o.x = s0; o.y = s1; o.z = s2; o.w = s3;
                *(float4*)&sLog[chunk*TC + (wv*2 + mt)*16 + quad*4] = o;
            }
        }
        __syncthreads();
    }

    // ---- softmax ----
    float lv[4];
    #pragma unroll
    for (int i = 0; i < 4; ++i) {
        int t = tid + i*256;
        lv[i] = sLog[t] + (1.0f - mask[(size_t)(b<<10) + t]) * (-3.402823466e+38f);
    }
    float m = fmaxf(fmaxf(lv[0], lv[1]), fmaxf(lv[2], lv[3]));
    #pragma unroll
    for (int off = 32; off; off >>= 1) m = fmaxf(m, __shfl_down(m, off, 64));
    if (lane == 0) sRed[wv] = m;
    __syncthreads();
    float M = fmaxf(fmaxf(sRed[0], sRed[1]), fmaxf(sRed[2], sRed[3]));
    float e[4]; float ssum = 0.f;
    #pragma unroll
    for (int i = 0; i < 4; ++i) { e[i] = expf(lv[i] - M); ssum += e[i]; }
    #pragma unroll
    for (int off = 32; off; off >>= 1) ssum += __shfl_down(ssum, off, 64);
    __syncthreads();
    if (lane == 0) sRed[wv] = ssum;
    __syncthreads();
    float inv = 1.0f / (sRed[0] + sRed[1] + sRed[2] + sRed[3]);
    #pragma unroll
    for (int i = 0; i < 4; ++i)
        probs[(size_t)row*SS + tid + i*256] = f2bf(e[i] * inv);
}

// ---------------- Kernel 3: split-K partial bf16 GEMM, 2-deep prefetch -----
// A: [2048][K] bf16. BT: [768][K] bf16 (+ optional batch stride).
// P[z][2048][768] f32 partials, z = split index (2 splits of K/2).
__global__ __launch_bounds__(256, 4) void k_mgemm_p(
    const unsigned short* __restrict__ A,
    const unsigned short* __restrict__ BT,
    float* __restrict__ P,
    int K, int bt_bstride)
{
    __shared__ __align__(16) unsigned short sA[2][64][72];
    __shared__ __align__(16) unsigned short sB[2][64][72];
    int tid = threadIdx.x;
    int w = tid >> 6, lane = tid & 63;
    int quad = lane >> 4, col = lane & 15;

    int m0 = blockIdx.y * 64, n0 = blockIdx.x * 64;
    int z = blockIdx.z;
    int kslice = K >> 1;
    int k0 = z * kslice;
    const unsigned short* Bb = BT + (size_t)(m0 >> 10) * bt_bstride;

    int r_a = tid >> 3, kc = tid & 7;        // load assignment (2 rows/thread)
    const unsigned short* Aptr = A  + (size_t)(m0 + r_a)*K + k0 + kc*8;
    const unsigned short* Bptr = Bb + (size_t)(n0 + r_a)*K + k0 + kc*8;
    const size_t half = (size_t)32*K;        // +32 rows

    floatx4 acc[4];
    #pragma unroll
    for (int nt = 0; nt < 4; ++nt) acc[nt] = (floatx4){0.f,0.f,0.f,0.f};

    uint4 ra[2][2], rb[2][2];
    int nk = kslice >> 6;

    // prologue: load stage 0 and 1, commit stage 0 to LDS
    #pragma unroll
    for (int st = 0; st < 2; ++st) {
        size_t off = (size_t)st*64;
        ra[st][0] = *(const uint4*)(Aptr + off);
        ra[st][1] = *(const uint4*)(Aptr + half + off);
        rb[st][0] = *(const uint4*)(Bptr + off);
        rb[st][1] = *(const uint4*)(Bptr + half + off);
    }
    *(uint4*)&sA[0][r_a][kc*8]      = ra[0][0];
    *(uint4*)&sA[0][r_a + 32][kc*8] = ra[0][1];
    *(uint4*)&sB[0][r_a][kc*8]      = rb[0][0];
    *(uint4*)&sB[0][r_a + 32][kc*8] = rb[0][1];
    __syncthreads();

    for (int kb = 0; kb < nk; ++kb) {
        int cur = kb & 1;
        if (kb + 2 < nk) {
            size_t off = (size_t)(kb + 2)*64;
            ra[cur][0] = *(const uint4*)(Aptr + off);
            ra[cur][1] = *(const uint4*)(Aptr + half + off);
            rb[cur][0] = *(const uint4*)(Bptr + off);
            rb[cur][1] = *(const uint4*)(Bptr + half + off);
        }
        #pragma unroll
        for (int kt = 0; kt < 2; ++kt) {
            short8 av = *(const short8*)&sA[cur][w*16 + col][kt*32 + quad*8];
            #pragma unroll
            for (int nt = 0; nt < 4; ++nt) {
                short8 bv = *(const short8*)&sB[cur][nt*16 + col][kt*32 + quad*8];
                acc[nt] = __builtin_amdgcn_mfma_f32_16x16x32_bf16(av, bv, acc[nt], 0, 0, 0);
            }
        }
        if (kb + 1 < nk) {
            int nxt = cur ^ 1;
            *(uint4*)&sA[nxt][r_a][kc*8]      = ra[nxt][0];
            *(uint4*)&sA[nxt][r_a + 32][kc*8] = ra[nxt][1];
            *(uint4*)&sB[nxt][r_a][kc*8]      = rb[nxt][0];
            *(uint4*)&sB[nxt][r_a + 32][kc*8] = rb[nxt][1];
        }
        __syncthreads();
    }

    float* Pz = P + (size_t)z*NRR*768;
    #pragma unroll
    for (int nt = 0; nt < 4; ++nt) {
        int n = n0 + nt*16 + col;
        #pragma unroll
        for (int r = 0; r < 4; ++r) {
            int m = w*16 + quad*4 + r;
            Pz[(size_t)(m0 + m)*768 + n] = acc[nt][r];
        }
    }
}

// ---------------- Kernel 4: reduce-epilogue --------------------------------
// MODE 0: msgin builder (ctx | hj | ctx*hj, bf16)
// MODE 1: Y1 = bf16(relu(sum + bias))    MODE 2: out = f32(alpha*(sum + bias))
template<int MODE>
__global__ __launch_bounds__(256) void k_epi(
    const float* __restrict__ P,
    const float* __restrict__ bias,
    const float* __restrict__ Hj,
    const float* __restrict__ alpha_p,
    void* __restrict__ Cout)
{
    int idx = blockIdx.x*256 + threadIdx.x;     // 0 .. 2048*192-1
    int g = idx / 192, c = (idx % 192) * 4;
    float4 v0 = *(const float4*)(P + (size_t)g*768 + c);
    float4 v1 = *(const float4*)(P + (size_t)NRR*768 + (size_t)g*768 + c);
    float v[4] = {v0.x+v1.x, v0.y+v1.y, v0.z+v1.z, v0.w+v1.w};
    if (MODE == 0) {
        float4 h4 = *(const float4*)(Hj + (size_t)g*HH + c);
        float hj[4] = {h4.x, h4.y, h4.z, h4.w};
        unsigned short* msgin = (unsigned short*)Cout;
        uint2 wc, wh, wp;
        wc.x = pack2(v[0], v[1]);        wc.y = pack2(v[2], v[3]);
        wh.x = pack2(hj[0], hj[1]);      wh.y = pack2(hj[2], hj[3]);
        wp.x = pack2(v[0]*hj[0], v[1]*hj[1]);
        wp.y = pack2(v[2]*hj[2], v[3]*hj[3]);
        *(uint2*)&msgin[(size_t)g*VINN + c]        = wc;
        *(uint2*)&msgin[(size_t)g*VINN + HH + c]   = wh;
        *(uint2*)&msgin[(size_t)g*VINN + 2*HH + c] = wp;
    } else if (MODE == 1) {
        float4 b4 = *(const float4*)(bias + c);
        uint2 wy;
        wy.x = pack2(fmaxf(v[0]+b4.x, 0.f), fmaxf(v[1]+b4.y, 0.f));
        wy.y = pack2(fmaxf(v[2]+b4.z, 0.f), fmaxf(v[3]+b4.w, 0.f));
        *(uint2*)&((unsigned short*)Cout)[(size_t)g*VHIDD + c] = wy;
    } else {
        float a = alpha_p[0];
        float4 b4 = *(const float4*)(bias + c);
        float4 o;
        o.x = a*(v[0]+b4.x); o.y = a*(v[1]+b4.y);
        o.z = a*(v[2]+b4.z); o.w = a*(v[3]+b4.w);
        *(float4*)&((float*)Cout)[(size_t)g*HH + c] = o;
    }
}

extern "C" void kernel_launch(void* const* d_in, const int* in_sizes, int n_in,
                              void* d_out, int out_size, void* d_ws, size_t ws_size,
                              hipStream_t stream)
{
    const float* Hj   = (const float*)d_in[0];
    const float* Hi   = (const float*)d_in[1];
    const float* mask = (const float*)d_in[2];
    const float* Wpj  = (const float*)d_in[3];
    const float* Wpi  = (const float*)d_in[4];
    const float* W1   = (const float*)d_in[5];
    const float* b1   = (const float*)d_in[6];
    const float* W2   = (const float*)d_in[7];
    const float* Wv1  = (const float*)d_in[9];
    const float* bv1  = (const float*)d_in[10];
    const float* Wv2  = (const float*)d_in[11];
    const float* bv2  = (const float*)d_in[12];
    const float* alpha = (const float*)d_in[13];
    float* out = (float*)d_out;

    const int NR = NRR;                   // 2048
    char* p = (char*)d_ws;
    auto alloc = [&](size_t bytes) {
        char* r = p; p += (bytes + 255) & ~(size_t)255; return r;
    };
    unsigned* Zjp          = (unsigned*)alloc((size_t)NR*12*4);
    unsigned* Zip          = (unsigned*)alloc((size_t)NR*12*4);
    unsigned short* probsb = (unsigned short*)alloc((size_t)NR*SS*2);
    unsigned short* HiT    = (unsigned short*)alloc((size_t)BB*HH*SS*2);
    unsigned short* Wv1T   = (unsigned short*)alloc((size_t)VHIDD*VINN*2);
    unsigned short* Wv2T   = (unsigned short*)alloc((size_t)HH*VHIDD*2);
    unsigned short* msginb = (unsigned short*)alloc((size_t)NR*VINN*2);
    unsigned short* Y1b    = (unsigned short*)alloc((size_t)NR*VHIDD*2);
    float* Part            = (float*)alloc((size_t)2*NR*768*4);

    k_tconv<<<dim3(VHIDD/32, VINN/32, 1), 256, 0, stream>>>(Wv1, Wv1T, VINN, VHIDD);
    k_tconv<<<dim3(HH/32, VHIDD/32, 1), 256, 0, stream>>>(Wv2, Wv2T, VHIDD, HH);
    k_tconv<<<dim3(HH/32, SS/32, BB), 256, 0, stream>>>(Hi, HiT, SS, HH);
    k_zproj<<<2*NR/64, 256, 0, stream>>>(Hj, Hi, Wpj, Wpi, Zjp, Zip);
    k_attn<<<NR, 256, 0, stream>>>(Zjp, Zip, W1, b1, W2, mask, probsb);

    const int EPI_GRID = NR*192/256;      // 1536

    // ctx GEMM: rows 2048 (b via bt stride), N=768, K=1024, split 2
    k_mgemm_p<<<dim3(HH/64, NR/64, 2), 256, 0, stream>>>(
        probsb, HiT, Part, SS, HH*SS);
    k_epi<0><<<EPI_GRID, 256, 0, stream>>>(Part, nullptr, Hj, alpha, msginb);

    // MLP GEMM1: K=2304, split 2
    k_mgemm_p<<<dim3(VHIDD/64, NR/64, 2), 256, 0, stream>>>(
        msginb, Wv1T, Part, VINN, 0);
    k_epi<1><<<EPI_GRID, 256, 0, stream>>>(Part, bv1, nullptr, alpha, Y1b);

    // MLP GEMM2: K=768, split 2
    k_mgemm_p<<<dim3(HH/64, NR/64, 2), 256, 0, stream>>>(
        Y1b, Wv2T, Part, VHIDD, 0);
    k_epi<2><<<EPI_GRID, 256, 0, stream>>>(Part, bv2, nullptr, alpha, out);
}

// Round 7
// 233.868 us; speedup vs baseline: 3.2576x; 1.3530x over previous
//
#include <hip/hip_runtime.h>
#include <math.h>

#define BB   2
#define SS   1024
#define HH   768
#define DD   24
#define HIDD 96
#define VINN 2304   // 3*H
#define VHIDD 768
#define NRR  2048   // BB*SS

typedef __attribute__((ext_vector_type(8))) short short8;
typedef __attribute__((ext_vector_type(4))) float floatx4;

static __device__ inline unsigned short f2bf(float x) {
    unsigned int u = __float_as_uint(x);
    u = (u + 0x7FFFu + ((u >> 16) & 1u)) >> 16;
    return (unsigned short)u;
}
static __device__ inline unsigned int pack2(float a, float b) {
    return (unsigned int)f2bf(a) | ((unsigned int)f2bf(b) << 16);
}

// async global -> LDS, 16 B per lane; LDS dest = wave-uniform base + lane*16
static __device__ inline void gl16(const unsigned short* g, unsigned short* l) {
    __builtin_amdgcn_global_load_lds(
        (const __attribute__((address_space(1))) unsigned int*)g,
        (__attribute__((address_space(3))) unsigned int*)l,
        16, 0, 0);
}

// ---------------- Kernel 0: f32 -> bf16 transpose-convert ------------------
__global__ __launch_bounds__(256) void k_tconv(
    const float* __restrict__ in, unsigned short* __restrict__ out,
    int R, int C)
{
    size_t zoff = (size_t)blockIdx.z * R * C;
    in += zoff; out += zoff;
    __shared__ float tile[32][33];
    int r0 = blockIdx.y * 32, c0 = blockIdx.x * 32;
    int tc = threadIdx.x & 31, tr = threadIdx.x >> 5;
    #pragma unroll
    for (int i = 0; i < 4; ++i)
        tile[tr + i*8][tc] = in[(size_t)(r0 + tr + i*8)*C + c0 + tc];
    __syncthreads();
    #pragma unroll
    for (int i = 0; i < 4; ++i)
        out[(size_t)(c0 + tr + i*8)*R + r0 + tc] = f2bf(tile[tc][tr + i*8]);
}

// ---------------- Kernel 1: Z projections via MFMA, packed-bf16 output -----
__global__ __launch_bounds__(256) void k_zproj(
    const float* __restrict__ Hj, const float* __restrict__ Hi,
    const float* __restrict__ Wpj, const float* __restrict__ Wpi,
    unsigned* __restrict__ Zjp, unsigned* __restrict__ Zip)
{
    __shared__ __align__(16) unsigned short sA[64][72];
    __shared__ __align__(16) unsigned short sBT[32][72];
    int tid = threadIdx.x;
    int w = tid >> 6, lane = tid & 63;
    int quad = lane >> 4, col = lane & 15;

    int m0 = blockIdx.x * 64;
    bool isJ = (m0 < NRR);
    const float* src = isJ ? Hj : Hi;
    const float* Wp  = isJ ? Wpj : Wpi;
    unsigned* Zp     = isJ ? Zjp : Zip;
    int rowbase = isJ ? m0 : (m0 - NRR);

    floatx4 acc[2];
    acc[0] = (floatx4){0.f,0.f,0.f,0.f};
    acc[1] = (floatx4){0.f,0.f,0.f,0.f};

    for (int kb = 0; kb < HH; kb += 64) {
        #pragma unroll
        for (int i = 0; i < 4; ++i) {
            int f4 = tid + i*256;
            int r = f4 >> 4, c4 = f4 & 15;
            float4 v = *(const float4*)(src + (size_t)(rowbase + r)*HH + kb + c4*4);
            uint2 pkt; pkt.x = pack2(v.x, v.y); pkt.y = pack2(v.z, v.w);
            *(uint2*)&sA[r][c4*4] = pkt;
        }
        {
            const float* wsrc = Wp + (size_t)kb*DD;
            #pragma unroll
            for (int i = 0; i < 6; ++i) {
                int idx = tid + i*256;
                int k = idx / DD, n = idx % DD;
                sBT[n][k] = f2bf(wsrc[idx]);
            }
        }
        __syncthreads();
        #pragma unroll
        for (int kt = 0; kt < 2; ++kt) {
            short8 av = *(const short8*)&sA[w*16 + col][kt*32 + quad*8];
            #pragma unroll
            for (int nt = 0; nt < 2; ++nt) {
                short8 bv = *(const short8*)&sBT[nt*16 + col][kt*32 + quad*8];
                acc[nt] = __builtin_amdgcn_mfma_f32_16x16x32_bf16(av, bv, acc[nt], 0, 0, 0);
            }
        }
        __syncthreads();
    }
    #pragma unroll
    for (int nt = 0; nt < 2; ++nt) {
        #pragma unroll
        for (int r = 0; r < 4; ++r) {
            float v = acc[nt][r];
            float vn = __shfl_xor(v, 1, 64);
            int n = nt*16 + col;
            if (!(col & 1) && n < DD) {
                int m = w*16 + quad*4 + r;
                Zp[(size_t)(rowbase + m)*12 + (n >> 1)] = pack2(v, vn);
            }
        }
    }
}

// ---------------- Kernel 2: MFMA logits + softmax -> probs (bf16) ----------
#define LSTR 72
#define TC 128
__global__ __launch_bounds__(256) void k_attn(
    const unsigned* __restrict__ Zjp, const unsigned* __restrict__ Zip,
    const float* __restrict__ W1, const float* __restrict__ b1,
    const float* __restrict__ W2,
    const float* __restrict__ mask, unsigned short* __restrict__ probs)
{
    int row = blockIdx.x;       // b*S + s
    int b = row >> 10;
    int tid = threadIdx.x;
    int lane = tid & 63, wv = tid >> 6;
    int quad = lane >> 4, col = lane & 15;

    __shared__ __align__(16) unsigned short sAB[128*LSTR];  // B-build, then A
    __shared__ __align__(16) float sLog[SS];
    __shared__ unsigned sZjp[12];
    __shared__ float sW2[HIDD];
    __shared__ float sRed[4];

    if (tid < 12) sZjp[tid] = Zjp[(size_t)row*12 + tid];
    if (tid < HIDD) sW2[tid] = W2[tid];
    __syncthreads();

    if (tid < HIDD) {
        int h = tid;
        float zj[24];
        #pragma unroll
        for (int u = 0; u < 12; ++u) {
            unsigned z = sZjp[u];
            zj[2*u]   = __uint_as_float(z << 16);
            zj[2*u+1] = __uint_as_float(z & 0xffff0000u);
        }
        float tj = b1[h];
        #pragma unroll
        for (int d = 0; d < DD; ++d) tj = fmaf(zj[d], W1[d*HIDD + h], tj);
        unsigned short* rowp = &sAB[h*LSTR];
        #pragma unroll
        for (int d = 0; d < DD; ++d)
            rowp[d] = f2bf(fmaf(zj[d], W1[(48+d)*HIDD + h], W1[(24+d)*HIDD + h]));
        #pragma unroll
        for (int d = 0; d < DD; ++d)
            rowp[24+d] = f2bf(W1[(72+d)*HIDD + h]);
        rowp[48] = f2bf(tj);
        #pragma unroll
        for (int k = 49; k < 64; ++k) rowp[k] = 0;
    }
    __syncthreads();

    short8 bfr[6][2];
    #pragma unroll
    for (int nf = 0; nf < 6; ++nf)
        #pragma unroll
        for (int kt = 0; kt < 2; ++kt)
            bfr[nf][kt] = *(const short8*)&sAB[(nf*16 + col)*LSTR + kt*32 + quad*8];
    float w2r[6];
    #pragma unroll
    for (int nf = 0; nf < 6; ++nf) w2r[nf] = sW2[col + nf*16];
    __syncthreads();   // sAB now reused as A

    int t_loc = tid >> 1, hh = tid & 1;
    const unsigned* zbase = Zip + (size_t)(b << 10) * 12;
    for (int chunk = 0; chunk < SS/TC; ++chunk) {
        {
            int t = chunk*TC + t_loc;
            const unsigned* zr = zbase + (size_t)t*12;
            unsigned short* rowp = &sAB[t_loc*LSTR];
            uint4 first = *(const uint4*)(zr + hh*4);
            *(uint4*)&rowp[hh*8] = first;
            uint4 second;
            if (hh) second = *(const uint4*)(zr + 8);
            else  { second.x = 0x3F80u; second.y = 0; second.z = 0; second.w = 0; }
            *(uint4*)&rowp[hh ? 16 : 48] = second;
            if (!hh) { uint4 zz; zz.x=0; zz.y=0; zz.z=0; zz.w=0; *(uint4*)&rowp[56] = zz; }
            uint2 ext; ext.x = 0; ext.y = 0;
            if (!hh) ext = *(const uint2*)(zr + 4);
            unsigned myz[6];
            if (hh) { myz[0]=first.z; myz[1]=first.w; myz[2]=second.x;
                      myz[3]=second.y; myz[4]=second.z; myz[5]=second.w; }
            else    { myz[0]=first.x; myz[1]=first.y; myz[2]=first.z;
                      myz[3]=first.w; myz[4]=ext.x;   myz[5]=ext.y; }
            unsigned q[6];
            #pragma unroll
            for (int u = 0; u < 6; ++u) {
                unsigned za = sZjp[hh*6 + u], zb = myz[u];
                float alo = __uint_as_float(za << 16);
                float ahi = __uint_as_float(za & 0xffff0000u);
                float blo = __uint_as_float(zb << 16);
                float bhi = __uint_as_float(zb & 0xffff0000u);
                unsigned dlo = __float_as_uint(fabsf(alo - blo)) + 0x8000u;
                unsigned dhi = __float_as_uint(fabsf(ahi - bhi)) + 0x8000u;
                q[u] = __builtin_amdgcn_perm(dhi, dlo, 0x07060302u);
            }
            #pragma unroll
            for (int j = 0; j < 3; ++j) {
                uint2 wq; wq.x = q[2*j]; wq.y = q[2*j+1];
                *(uint2*)&rowp[24 + hh*12 + 4*j] = wq;
            }
        }
        __syncthreads();

        #pragma unroll
        for (int mt = 0; mt < 2; ++mt) {
            int arow = (wv*2 + mt)*16 + col;
            const unsigned short* ar = &sAB[arow*LSTR];
            short8 a0 = *(const short8*)&ar[quad*8];
            short8 a1 = *(const short8*)&ar[32 + quad*8];
            float s0 = 0.f, s1 = 0.f, s2 = 0.f, s3 = 0.f;
            #pragma unroll
            for (int nf = 0; nf < 6; ++nf) {
                floatx4 acc = {0.f, 0.f, 0.f, 0.f};
                acc = __builtin_amdgcn_mfma_f32_16x16x32_bf16(a0, bfr[nf][0], acc, 0, 0, 0);
                acc = __builtin_amdgcn_mfma_f32_16x16x32_bf16(a1, bfr[nf][1], acc, 0, 0, 0);
                float w2v = w2r[nf];
                s0 = fmaf(fmaxf(acc[0], 0.f), w2v, s0);
                s1 = fmaf(fmaxf(acc[1], 0.f), w2v, s1);
                s2 = fmaf(fmaxf(acc[2], 0.f), w2v, s2);
                s3 = fmaf(fmaxf(acc[3], 0.f), w2v, s3);
            }
            #pragma unroll
            for (int m = 1; m < 16; m <<= 1) {
                s0 += __shfl_xor(s0, m, 64);
                s1 += __shfl_xor(s1, m, 64);
                s2 += __shfl_xor(s2, m, 64);
                s3 += __shfl_xor(s3, m, 64);
            }
            if (col == 0) {
                float4 o; o.x = s0; o.y = s1; o.z = s2; o.w = s3;
                *(float4*)&sLog[chunk*TC + (wv*2 + mt)*16 + quad*4] = o;
            }
        }
        __syncthreads();
    }

    // ---- softmax ----
    float lv[4];
    #pragma unroll
    for (int i = 0; i < 4; ++i) {
        int t = tid + i*256;
        lv[i] = sLog[t] + (1.0f - mask[(size_t)(b<<10) + t]) * (-3.402823466e+38f);
    }
    float m = fmaxf(fmaxf(lv[0], lv[1]), fmaxf(lv[2], lv[3]));
    #pragma unroll
    for (int off = 32; off; off >>= 1) m = fmaxf(m, __shfl_down(m, off, 64));
    if (lane == 0) sRed[wv] = m;
    __syncthreads();
    float M = fmaxf(fmaxf(sRed[0], sRed[1]), fmaxf(sRed[2], sRed[3]));
    float e[4]; float ssum = 0.f;
    #pragma unroll
    for (int i = 0; i < 4; ++i) { e[i] = expf(lv[i] - M); ssum += e[i]; }
    #pragma unroll
    for (int off = 32; off; off >>= 1) ssum += __shfl_down(ssum, off, 64);
    __syncthreads();
    if (lane == 0) sRed[wv] = ssum;
    __syncthreads();
    float inv = 1.0f / (sRed[0] + sRed[1] + sRed[2] + sRed[3]);
    #pragma unroll
    for (int i = 0; i < 4; ++i)
        probs[(size_t)row*SS + tid + i*256] = f2bf(e[i] * inv);
}

// ---------------- Kernel 3: m97-style split-K partial GEMM -----------------
// 128x128 tile, BK=64, global_load_lds(16B), 2-barrier K-loop.
// A: [2048][K] bf16. BT: [768][K] bf16 (+ batch stride). Split-K = 4.
// P[z][2048][768] f32 partials.
__global__ __launch_bounds__(256) void k_mgemm_p(
    const unsigned short* __restrict__ A,
    const unsigned short* __restrict__ BT,
    float* __restrict__ P,
    int K, int bt_bstride)
{
    __shared__ __align__(16) unsigned short sA[128*64];
    __shared__ __align__(16) unsigned short sB[128*64];
    int tid = threadIdx.x;
    int w = tid >> 6, lane = tid & 63;
    int quad = lane >> 4, col = lane & 15;

    int n0 = blockIdx.x * 128, m0 = blockIdx.y * 128;
    int z = blockIdx.z;
    int kslice = K >> 2;
    int k0 = z * kslice;
    int nk = kslice >> 6;
    const unsigned short* Bb = BT + (size_t)(m0 >> 10) * bt_bstride;

    int srow = lane >> 3;          // 0..7 within the 8-row staging group
    int skc  = (lane & 7) * 8;     // ushort offset within row

    floatx4 acc[2][8];
    #pragma unroll
    for (int mt = 0; mt < 2; ++mt)
        #pragma unroll
        for (int nf = 0; nf < 8; ++nf)
            acc[mt][nf] = (floatx4){0.f,0.f,0.f,0.f};

    for (int kb = 0; kb < nk; ++kb) {
        int kofs = k0 + kb*64;
        #pragma unroll
        for (int i = 0; i < 4; ++i) {
            int rbase = w*8 + i*32;
            gl16(A  + (size_t)(m0 + rbase + srow)*K + kofs + skc, &sA[rbase*64]);
            gl16(Bb + (size_t)(n0 + rbase + srow)*K + kofs + skc, &sB[rbase*64]);
        }
        __syncthreads();
        #pragma unroll
        for (int kt = 0; kt < 2; ++kt) {
            short8 av[2];
            #pragma unroll
            for (int mt = 0; mt < 2; ++mt)
                av[mt] = *(const short8*)&sA[(w*32 + mt*16 + col)*64 + kt*32 + quad*8];
            #pragma unroll
            for (int nf = 0; nf < 8; ++nf) {
                short8 bv = *(const short8*)&sB[(nf*16 + col)*64 + kt*32 + quad*8];
                #pragma unroll
                for (int mt = 0; mt < 2; ++mt)
                    acc[mt][nf] = __builtin_amdgcn_mfma_f32_16x16x32_bf16(
                        av[mt], bv, acc[mt][nf], 0, 0, 0);
            }
        }
        __syncthreads();
    }

    float* Pz = P + (size_t)z*NRR*768;
    #pragma unroll
    for (int mt = 0; mt < 2; ++mt) {
        #pragma unroll
        for (int nf = 0; nf < 8; ++nf) {
            int n = n0 + nf*16 + col;
            #pragma unroll
            for (int r = 0; r < 4; ++r) {
                int m = w*32 + mt*16 + quad*4 + r;
                Pz[(size_t)(m0 + m)*768 + n] = acc[mt][nf][r];
            }
        }
    }
}

// ---------------- Kernel 4: reduce-epilogue (4 partials) -------------------
// MODE 0: msgin builder (ctx | hj | ctx*hj, bf16)
// MODE 1: Y1 = bf16(relu(sum + bias))    MODE 2: out = f32(alpha*(sum + bias))
template<int MODE>
__global__ __launch_bounds__(256) void k_epi(
    const float* __restrict__ P,
    const float* __restrict__ bias,
    const float* __restrict__ Hj,
    const float* __restrict__ alpha_p,
    void* __restrict__ Cout)
{
    int idx = blockIdx.x*256 + threadIdx.x;     // 0 .. 2048*192-1
    int g = idx / 192, c = (idx % 192) * 4;
    float v[4] = {0.f, 0.f, 0.f, 0.f};
    #pragma unroll
    for (int z = 0; z < 4; ++z) {
        float4 vz = *(const float4*)(P + (size_t)z*NRR*768 + (size_t)g*768 + c);
        v[0] += vz.x; v[1] += vz.y; v[2] += vz.z; v[3] += vz.w;
    }
    if (MODE == 0) {
        float4 h4 = *(const float4*)(Hj + (size_t)g*HH + c);
        float hj[4] = {h4.x, h4.y, h4.z, h4.w};
        unsigned short* msgin = (unsigned short*)Cout;
        uint2 wc, wh, wp;
        wc.x = pack2(v[0], v[1]);        wc.y = pack2(v[2], v[3]);
        wh.x = pack2(hj[0], hj[1]);      wh.y = pack2(hj[2], hj[3]);
        wp.x = pack2(v[0]*hj[0], v[1]*hj[1]);
        wp.y = pack2(v[2]*hj[2], v[3]*hj[3]);
        *(uint2*)&msgin[(size_t)g*VINN + c]        = wc;
        *(uint2*)&msgin[(size_t)g*VINN + HH + c]   = wh;
        *(uint2*)&msgin[(size_t)g*VINN + 2*HH + c] = wp;
    } else if (MODE == 1) {
        float4 b4 = *(const float4*)(bias + c);
        uint2 wy;
        wy.x = pack2(fmaxf(v[0]+b4.x, 0.f), fmaxf(v[1]+b4.y, 0.f));
        wy.y = pack2(fmaxf(v[2]+b4.z, 0.f), fmaxf(v[3]+b4.w, 0.f));
        *(uint2*)&((unsigned short*)Cout)[(size_t)g*VHIDD + c] = wy;
    } else {
        float a = alpha_p[0];
        float4 b4 = *(const float4*)(bias + c);
        float4 o;
        o.x = a*(v[0]+b4.x); o.y = a*(v[1]+b4.y);
        o.z = a*(v[2]+b4.z); o.w = a*(v[3]+b4.w);
        *(float4*)&((float*)Cout)[(size_t)g*HH + c] = o;
    }
}

extern "C" void kernel_launch(void* const* d_in, const int* in_sizes, int n_in,
                              void* d_out, int out_size, void* d_ws, size_t ws_size,
                              hipStream_t stream)
{
    const float* Hj   = (const float*)d_in[0];
    const float* Hi   = (const float*)d_in[1];
    const float* mask = (const float*)d_in[2];
    const float* Wpj  = (const float*)d_in[3];
    const float* Wpi  = (const float*)d_in[4];
    const float* W1   = (const float*)d_in[5];
    const float* b1   = (const float*)d_in[6];
    const float* W2   = (const float*)d_in[7];
    const float* Wv1  = (const float*)d_in[9];
    const float* bv1  = (const float*)d_in[10];
    const float* Wv2  = (const float*)d_in[11];
    const float* bv2  = (const float*)d_in[12];
    const float* alpha = (const float*)d_in[13];
    float* out = (float*)d_out;

    const int NR = NRR;                   // 2048
    char* p = (char*)d_ws;
    auto alloc = [&](size_t bytes) {
        char* r = p; p += (bytes + 255) & ~(size_t)255; return r;
    };
    unsigned* Zjp          = (unsigned*)alloc((size_t)NR*12*4);
    unsigned* Zip          = (unsigned*)alloc((size_t)NR*12*4);
    unsigned short* probsb = (unsigned short*)alloc((size_t)NR*SS*2);
    unsigned short* HiT    = (unsigned short*)alloc((size_t)BB*HH*SS*2);
    unsigned short* Wv1T   = (unsigned short*)alloc((size_t)VHIDD*VINN*2);
    unsigned short* Wv2T   = (unsigned short*)alloc((size_t)HH*VHIDD*2);
    unsigned short* msginb = (unsigned short*)alloc((size_t)NR*VINN*2);
    unsigned short* Y1b    = (unsigned short*)alloc((size_t)NR*VHIDD*2);
    float* Part            = (float*)alloc((size_t)4*NR*768*4);

    k_tconv<<<dim3(VHIDD/32, VINN/32, 1), 256, 0, stream>>>(Wv1, Wv1T, VINN, VHIDD);
    k_tconv<<<dim3(HH/32, VHIDD/32, 1), 256, 0, stream>>>(Wv2, Wv2T, VHIDD, HH);
    k_tconv<<<dim3(HH/32, SS/32, BB), 256, 0, stream>>>(Hi, HiT, SS, HH);
    k_zproj<<<2*NR/64, 256, 0, stream>>>(Hj, Hi, Wpj, Wpi, Zjp, Zip);
    k_attn<<<NR, 256, 0, stream>>>(Zjp, Zip, W1, b1, W2, mask, probsb);

    const int EPI_GRID = NR*192/256;      // 1536

    // ctx GEMM: M=2048 (batch via bt stride), N=768, K=1024, split 4
    k_mgemm_p<<<dim3(HH/128, NR/128, 4), 256, 0, stream>>>(
        probsb, HiT, Part, SS, HH*SS);
    k_epi<0><<<EPI_GRID, 256, 0, stream>>>(Part, nullptr, Hj, alpha, msginb);

    // MLP GEMM1: K=2304, split 4
    k_mgemm_p<<<dim3(VHIDD/128, NR/128, 4), 256, 0, stream>>>(
        msginb, Wv1T, Part, VINN, 0);
    k_epi<1><<<EPI_GRID, 256, 0, stream>>>(Part, bv1, nullptr, alpha, Y1b);

    // MLP GEMM2: K=768, split 4
    k_mgemm_p<<<dim3(HH/128, NR/128, 4), 256, 0, stream>>>(
        Y1b, Wv2T, Part, VHIDD, 0);
    k_epi<2><<<EPI_GRID, 256, 0, stream>>>(Part, bv2, nullptr, alpha, out);
}

// Round 8
// 227.484 us; speedup vs baseline: 3.3490x; 1.0281x over previous
//
#include <hip/hip_runtime.h>
#include <math.h>

#define BB   2
#define SS   1024
#define HH   768
#define DD   24
#define HIDD 96
#define VINN 2304   // 3*H
#define VHIDD 768
#define NRR  2048   // BB*SS

typedef __attribute__((ext_vector_type(8))) short short8;
typedef __attribute__((ext_vector_type(4))) float floatx4;

static __device__ inline unsigned short f2bf(float x) {
    unsigned int u = __float_as_uint(x);
    u = (u + 0x7FFFu + ((u >> 16) & 1u)) >> 16;
    return (unsigned short)u;
}
static __device__ inline unsigned int pack2(float a, float b) {
    return (unsigned int)f2bf(a) | ((unsigned int)f2bf(b) << 16);
}

// async global -> LDS, 16 B per lane; LDS dest = wave-uniform base + lane*16
static __device__ inline void gl16(const unsigned short* g, unsigned short* l) {
    __builtin_amdgcn_global_load_lds(
        (const __attribute__((address_space(1))) unsigned int*)g,
        (__attribute__((address_space(3))) unsigned int*)l,
        16, 0, 0);
}

// ---------------- Kernel 0: f32 -> bf16 transpose-convert ------------------
__global__ __launch_bounds__(256) void k_tconv(
    const float* __restrict__ in, unsigned short* __restrict__ out,
    int R, int C)
{
    size_t zoff = (size_t)blockIdx.z * R * C;
    in += zoff; out += zoff;
    __shared__ float tile[32][33];
    int r0 = blockIdx.y * 32, c0 = blockIdx.x * 32;
    int tc = threadIdx.x & 31, tr = threadIdx.x >> 5;
    #pragma unroll
    for (int i = 0; i < 4; ++i)
        tile[tr + i*8][tc] = in[(size_t)(r0 + tr + i*8)*C + c0 + tc];
    __syncthreads();
    #pragma unroll
    for (int i = 0; i < 4; ++i)
        out[(size_t)(c0 + tr + i*8)*R + r0 + tc] = f2bf(tile[tc][tr + i*8]);
}

// ---------------- Kernel 1: Z projections via MFMA, packed-bf16 output -----
__global__ __launch_bounds__(256) void k_zproj(
    const float* __restrict__ Hj, const float* __restrict__ Hi,
    const float* __restrict__ Wpj, const float* __restrict__ Wpi,
    unsigned* __restrict__ Zjp, unsigned* __restrict__ Zip)
{
    __shared__ __align__(16) unsigned short sA[64][72];
    __shared__ __align__(16) unsigned short sBT[32][72];
    int tid = threadIdx.x;
    int w = tid >> 6, lane = tid & 63;
    int quad = lane >> 4, col = lane & 15;

    int m0 = blockIdx.x * 64;
    bool isJ = (m0 < NRR);
    const float* src = isJ ? Hj : Hi;
    const float* Wp  = isJ ? Wpj : Wpi;
    unsigned* Zp     = isJ ? Zjp : Zip;
    int rowbase = isJ ? m0 : (m0 - NRR);

    floatx4 acc[2];
    acc[0] = (floatx4){0.f,0.f,0.f,0.f};
    acc[1] = (floatx4){0.f,0.f,0.f,0.f};

    for (int kb = 0; kb < HH; kb += 64) {
        #pragma unroll
        for (int i = 0; i < 4; ++i) {
            int f4 = tid + i*256;
            int r = f4 >> 4, c4 = f4 & 15;
            float4 v = *(const float4*)(src + (size_t)(rowbase + r)*HH + kb + c4*4);
            uint2 pkt; pkt.x = pack2(v.x, v.y); pkt.y = pack2(v.z, v.w);
            *(uint2*)&sA[r][c4*4] = pkt;
        }
        {
            const float* wsrc = Wp + (size_t)kb*DD;
            #pragma unroll
            for (int i = 0; i < 6; ++i) {
                int idx = tid + i*256;
                int k = idx / DD, n = idx % DD;
                sBT[n][k] = f2bf(wsrc[idx]);
            }
        }
        __syncthreads();
        #pragma unroll
        for (int kt = 0; kt < 2; ++kt) {
            short8 av = *(const short8*)&sA[w*16 + col][kt*32 + quad*8];
            #pragma unroll
            for (int nt = 0; nt < 2; ++nt) {
                short8 bv = *(const short8*)&sBT[nt*16 + col][kt*32 + quad*8];
                acc[nt] = __builtin_amdgcn_mfma_f32_16x16x32_bf16(av, bv, acc[nt], 0, 0, 0);
            }
        }
        __syncthreads();
    }
    #pragma unroll
    for (int nt = 0; nt < 2; ++nt) {
        #pragma unroll
        for (int r = 0; r < 4; ++r) {
            float v = acc[nt][r];
            float vn = __shfl_xor(v, 1, 64);
            int n = nt*16 + col;
            if (!(col & 1) && n < DD) {
                int m = w*16 + quad*4 + r;
                Zp[(size_t)(rowbase + m)*12 + (n >> 1)] = pack2(v, vn);
            }
        }
    }
}

// ---------------- Kernel 2: MFMA logits + softmax -> probs (bf16) ----------
// Operand-swapped MFMA: D[m=h][n=t] = mfma(bfr(h-side), av(t-side)).
// Per-lane fold over (hf, reg) replaces the 16-lane butterfly; cross-quad
// reduce is 2 shuffles. A-chunk region double-buffered: 1 barrier/chunk.
#define LSTR 72
#define TC 128
__global__ __launch_bounds__(256) void k_attn(
    const unsigned* __restrict__ Zjp, const unsigned* __restrict__ Zip,
    const float* __restrict__ W1, const float* __restrict__ b1,
    const float* __restrict__ W2,
    const float* __restrict__ mask, unsigned short* __restrict__ probs)
{
    int row = blockIdx.x;       // b*S + s
    int b = row >> 10;
    int tid = threadIdx.x;
    int lane = tid & 63, wv = tid >> 6;
    int quad = lane >> 4, col = lane & 15;

    __shared__ __align__(16) unsigned short sAB[2][TC*LSTR]; // B-build in [0], then A dbuf
    __shared__ __align__(16) float sLog[SS];
    __shared__ unsigned sZjp[12];
    __shared__ float sW2[HIDD];
    __shared__ float sRed[4];

    if (tid < 12) sZjp[tid] = Zjp[(size_t)row*12 + tid];
    if (tid < HIDD) sW2[tid] = W2[tid];
    __syncthreads();

    // ---- build B in sAB[0] (rows h = 0..95, k = 0..63) ----
    if (tid < HIDD) {
        int h = tid;
        float zj[24];
        #pragma unroll
        for (int u = 0; u < 12; ++u) {
            unsigned z = sZjp[u];
            zj[2*u]   = __uint_as_float(z << 16);
            zj[2*u+1] = __uint_as_float(z & 0xffff0000u);
        }
        float tj = b1[h];
        #pragma unroll
        for (int d = 0; d < DD; ++d) tj = fmaf(zj[d], W1[d*HIDD + h], tj);
        unsigned short* rowp = &sAB[0][h*LSTR];
        #pragma unroll
        for (int d = 0; d < DD; ++d)
            rowp[d] = f2bf(fmaf(zj[d], W1[(48+d)*HIDD + h], W1[(24+d)*HIDD + h]));
        #pragma unroll
        for (int d = 0; d < DD; ++d)
            rowp[24+d] = f2bf(W1[(72+d)*HIDD + h]);
        rowp[48] = f2bf(tj);
        #pragma unroll
        for (int k = 49; k < 64; ++k) rowp[k] = 0;
    }
    __syncthreads();

    // hoist B fragments (h-side, used as MFMA A-operand) + per-lane w2 coeffs
    short8 bfr[6][2];
    #pragma unroll
    for (int nf = 0; nf < 6; ++nf)
        #pragma unroll
        for (int kt = 0; kt < 2; ++kt)
            bfr[nf][kt] = *(const short8*)&sAB[0][(nf*16 + col)*LSTR + kt*32 + quad*8];
    float4 w2q[6];
    #pragma unroll
    for (int nf = 0; nf < 6; ++nf)
        w2q[nf] = *(const float4*)&sW2[nf*16 + quad*4];
    __syncthreads();   // sAB now reused as A double-buffer

    // constant region k=48..63 (written once per buffer)
    {
        int r = tid >> 1, bf = tid & 1;     // 128 rows x 2 buffers
        unsigned short* rowp = &sAB[bf][r*LSTR];
        uint4 w0; w0.x = 0x3F80u; w0.y = 0; w0.z = 0; w0.w = 0;
        *(uint4*)&rowp[48] = w0;
        uint4 zz; zz.x = 0; zz.y = 0; zz.z = 0; zz.w = 0;
        *(uint4*)&rowp[56] = zz;
    }

    int t_loc = tid >> 1, hh = tid & 1;
    const unsigned* zbase = Zip + (size_t)(b << 10) * 12;

    // A-pack for one chunk into buffer bf (k 0..47 only)
    auto pack = [&](int chunk, int bf) {
        int t = chunk*TC + t_loc;
        const unsigned* zr = zbase + (size_t)t*12;
        unsigned short* rowp = &sAB[bf][t_loc*LSTR];
        uint4 first = *(const uint4*)(zr + hh*4);
        *(uint4*)&rowp[hh*8] = first;
        uint2 ext; ext.x = 0; ext.y = 0;
        if (hh) {
            uint4 second = *(const uint4*)(zr + 8);
            *(uint4*)&rowp[16] = second;
            unsigned myz[6] = {first.z, first.w, second.x, second.y, second.z, second.w};
            unsigned q[6];
            #pragma unroll
            for (int u = 0; u < 6; ++u) {
                unsigned za = sZjp[6 + u], zb = myz[u];
                float alo = __uint_as_float(za << 16);
                float ahi = __uint_as_float(za & 0xffff0000u);
                float blo = __uint_as_float(zb << 16);
                float bhi = __uint_as_float(zb & 0xffff0000u);
                unsigned dlo = __float_as_uint(fabsf(alo - blo)) + 0x8000u;
                unsigned dhi = __float_as_uint(fabsf(ahi - bhi)) + 0x8000u;
                q[u] = __builtin_amdgcn_perm(dhi, dlo, 0x07060302u);
            }
            #pragma unroll
            for (int j = 0; j < 3; ++j) {
                uint2 wq; wq.x = q[2*j]; wq.y = q[2*j+1];
                *(uint2*)&rowp[36 + 4*j] = wq;
            }
        } else {
            ext = *(const uint2*)(zr + 4);
            unsigned myz[6] = {first.x, first.y, first.z, first.w, ext.x, ext.y};
            unsigned q[6];
            #pragma unroll
            for (int u = 0; u < 6; ++u) {
                unsigned za = sZjp[u], zb = myz[u];
                float alo = __uint_as_float(za << 16);
                float ahi = __uint_as_float(za & 0xffff0000u);
                float blo = __uint_as_float(zb << 16);
                float bhi = __uint_as_float(zb & 0xffff0000u);
                unsigned dlo = __float_as_uint(fabsf(alo - blo)) + 0x8000u;
                unsigned dhi = __float_as_uint(fabsf(ahi - bhi)) + 0x8000u;
                q[u] = __builtin_amdgcn_perm(dhi, dlo, 0x07060302u);
            }
            #pragma unroll
            for (int j = 0; j < 3; ++j) {
                uint2 wq; wq.x = q[2*j]; wq.y = q[2*j+1];
                *(uint2*)&rowp[24 + 4*j] = wq;
            }
        }
    };

    pack(0, 0);
    __syncthreads();

    for (int chunk = 0; chunk < SS/TC; ++chunk) {
        int cur = chunk & 1;
        if (chunk + 1 < SS/TC) pack(chunk + 1, cur ^ 1);

        // MFMA: D[h][t]; per-lane fold over (hf, reg), cross-quad reduce
        short8 av[2][2];
        #pragma unroll
        for (int tt = 0; tt < 2; ++tt) {
            int arow = (wv*2 + tt)*16 + col;
            av[tt][0] = *(const short8*)&sAB[cur][arow*LSTR + quad*8];
            av[tt][1] = *(const short8*)&sAB[cur][arow*LSTR + 32 + quad*8];
        }
        float s0 = 0.f, s1 = 0.f;
        #pragma unroll
        for (int hf = 0; hf < 6; ++hf) {
            floatx4 a0 = {0.f,0.f,0.f,0.f}, a1 = {0.f,0.f,0.f,0.f};
            a0 = __builtin_amdgcn_mfma_f32_16x16x32_bf16(bfr[hf][0], av[0][0], a0, 0, 0, 0);
            a0 = __builtin_amdgcn_mfma_f32_16x16x32_bf16(bfr[hf][1], av[0][1], a0, 0, 0, 0);
            a1 = __builtin_amdgcn_mfma_f32_16x16x32_bf16(bfr[hf][0], av[1][0], a1, 0, 0, 0);
            a1 = __builtin_amdgcn_mfma_f32_16x16x32_bf16(bfr[hf][1], av[1][1], a1, 0, 0, 0);
            float w2v[4] = {w2q[hf].x, w2q[hf].y, w2q[hf].z, w2q[hf].w};
            #pragma unroll
            for (int r = 0; r < 4; ++r) {
                s0 = fmaf(fmaxf(a0[r], 0.f), w2v[r], s0);
                s1 = fmaf(fmaxf(a1[r], 0.f), w2v[r], s1);
            }
        }
        s0 += __shfl_xor(s0, 16, 64);  s0 += __shfl_xor(s0, 32, 64);
        s1 += __shfl_xor(s1, 16, 64);  s1 += __shfl_xor(s1, 32, 64);
        if (lane < 16) {
            sLog[chunk*TC + (wv*2 + 0)*16 + lane] = s0;
            sLog[chunk*TC + (wv*2 + 1)*16 + lane] = s1;
        }
        __syncthreads();
    }

    // ---- softmax ----
    float lv[4];
    #pragma unroll
    for (int i = 0; i < 4; ++i) {
        int t = tid + i*256;
        lv[i] = sLog[t] + (1.0f - mask[(size_t)(b<<10) + t]) * (-3.402823466e+38f);
    }
    float m = fmaxf(fmaxf(lv[0], lv[1]), fmaxf(lv[2], lv[3]));
    #pragma unroll
    for (int off = 32; off; off >>= 1) m = fmaxf(m, __shfl_down(m, off, 64));
    if (lane == 0) sRed[wv] = m;
    __syncthreads();
    float M = fmaxf(fmaxf(sRed[0], sRed[1]), fmaxf(sRed[2], sRed[3]));
    float e[4]; float ssum = 0.f;
    #pragma unroll
    for (int i = 0; i < 4; ++i) { e[i] = expf(lv[i] - M); ssum += e[i]; }
    #pragma unroll
    for (int off = 32; off; off >>= 1) ssum += __shfl_down(ssum, off, 64);
    __syncthreads();
    if (lane == 0) sRed[wv] = ssum;
    __syncthreads();
    float inv = 1.0f / (sRed[0] + sRed[1] + sRed[2] + sRed[3]);
    #pragma unroll
    for (int i = 0; i < 4; ++i)
        probs[(size_t)row*SS + tid + i*256] = f2bf(e[i] * inv);
}

// ---------------- Kernel 3: m97-style split-K partial GEMM -----------------
// 128x128 tile, BK=64, global_load_lds(16B), 2-barrier K-loop.
// A: [2048][K] bf16. BT: [768][K] bf16 (+ batch stride). Split-K = 4.
// P[z][2048][768] f32 partials.
__global__ __launch_bounds__(256) void k_mgemm_p(
    const unsigned short* __restrict__ A,
    const unsigned short* __restrict__ BT,
    float* __restrict__ P,
    int K, int bt_bstride)
{
    __shared__ __align__(16) unsigned short sA[128*64];
    __shared__ __align__(16) unsigned short sB[128*64];
    int tid = threadIdx.x;
    int w = tid >> 6, lane = tid & 63;
    int quad = lane >> 4, col = lane & 15;

    int n0 = blockIdx.x * 128, m0 = blockIdx.y * 128;
    int z = blockIdx.z;
    int kslice = K >> 2;
    int k0 = z * kslice;
    int nk = kslice >> 6;
    const unsigned short* Bb = BT + (size_t)(m0 >> 10) * bt_bstride;

    int srow = lane >> 3;          // 0..7 within the 8-row staging group
    int skc  = (lane & 7) * 8;     // ushort offset within row

    floatx4 acc[2][8];
    #pragma unroll
    for (int mt = 0; mt < 2; ++mt)
        #pragma unroll
        for (int nf = 0; nf < 8; ++nf)
            acc[mt][nf] = (floatx4){0.f,0.f,0.f,0.f};

    for (int kb = 0; kb < nk; ++kb) {
        int kofs = k0 + kb*64;
        #pragma unroll
        for (int i = 0; i < 4; ++i) {
            int rbase = w*8 + i*32;
            gl16(A  + (size_t)(m0 + rbase + srow)*K + kofs + skc, &sA[rbase*64]);
            gl16(Bb + (size_t)(n0 + rbase + srow)*K + kofs + skc, &sB[rbase*64]);
        }
        __syncthreads();
        #pragma unroll
        for (int kt = 0; kt < 2; ++kt) {
            short8 av[2];
            #pragma unroll
            for (int mt = 0; mt < 2; ++mt)
                av[mt] = *(const short8*)&sA[(w*32 + mt*16 + col)*64 + kt*32 + quad*8];
            #pragma unroll
            for (int nf = 0; nf < 8; ++nf) {
                short8 bv = *(const short8*)&sB[(nf*16 + col)*64 + kt*32 + quad*8];
                #pragma unroll
                for (int mt = 0; mt < 2; ++mt)
                    acc[mt][nf] = __builtin_amdgcn_mfma_f32_16x16x32_bf16(
                        av[mt], bv, acc[mt][nf], 0, 0, 0);
            }
        }
        __syncthreads();
    }

    float* Pz = P + (size_t)z*NRR*768;
    #pragma unroll
    for (int mt = 0; mt < 2; ++mt) {
        #pragma unroll
        for (int nf = 0; nf < 8; ++nf) {
            int n = n0 + nf*16 + col;
            #pragma unroll
            for (int r = 0; r < 4; ++r) {
                int m = w*32 + mt*16 + quad*4 + r;
                Pz[(size_t)(m0 + m)*768 + n] = acc[mt][nf][r];
            }
        }
    }
}

// ---------------- Kernel 4: reduce-epilogue (4 partials) -------------------
// MODE 0: msgin builder (ctx | hj | ctx*hj, bf16)
// MODE 1: Y1 = bf16(relu(sum + bias))    MODE 2: out = f32(alpha*(sum + bias))
template<int MODE>
__global__ __launch_bounds__(256) void k_epi(
    const float* __restrict__ P,
    const float* __restrict__ bias,
    const float* __restrict__ Hj,
    const float* __restrict__ alpha_p,
    void* __restrict__ Cout)
{
    int idx = blockIdx.x*256 + threadIdx.x;     // 0 .. 2048*192-1
    int g = idx / 192, c = (idx % 192) * 4;
    float v[4] = {0.f, 0.f, 0.f, 0.f};
    #pragma unroll
    for (int z = 0; z < 4; ++z) {
        float4 vz = *(const float4*)(P + (size_t)z*NRR*768 + (size_t)g*768 + c);
        v[0] += vz.x; v[1] += vz.y; v[2] += vz.z; v[3] += vz.w;
    }
    if (MODE == 0) {
        float4 h4 = *(const float4*)(Hj + (size_t)g*HH + c);
        float hj[4] = {h4.x, h4.y, h4.z, h4.w};
        unsigned short* msgin = (unsigned short*)Cout;
        uint2 wc, wh, wp;
        wc.x = pack2(v[0], v[1]);        wc.y = pack2(v[2], v[3]);
        wh.x = pack2(hj[0], hj[1]);      wh.y = pack2(hj[2], hj[3]);
        wp.x = pack2(v[0]*hj[0], v[1]*hj[1]);
        wp.y = pack2(v[2]*hj[2], v[3]*hj[3]);
        *(uint2*)&msgin[(size_t)g*VINN + c]        = wc;
        *(uint2*)&msgin[(size_t)g*VINN + HH + c]   = wh;
        *(uint2*)&msgin[(size_t)g*VINN + 2*HH + c] = wp;
    } else if (MODE == 1) {
        float4 b4 = *(const float4*)(bias + c);
        uint2 wy;
        wy.x = pack2(fmaxf(v[0]+b4.x, 0.f), fmaxf(v[1]+b4.y, 0.f));
        wy.y = pack2(fmaxf(v[2]+b4.z, 0.f), fmaxf(v[3]+b4.w, 0.f));
        *(uint2*)&((unsigned short*)Cout)[(size_t)g*VHIDD + c] = wy;
    } else {
        float a = alpha_p[0];
        float4 b4 = *(const float4*)(bias + c);
        float4 o;
        o.x = a*(v[0]+b4.x); o.y = a*(v[1]+b4.y);
        o.z = a*(v[2]+b4.z); o.w = a*(v[3]+b4.w);
        *(float4*)&((float*)Cout)[(size_t)g*HH + c] = o;
    }
}

extern "C" void kernel_launch(void* const* d_in, const int* in_sizes, int n_in,
                              void* d_out, int out_size, void* d_ws, size_t ws_size,
                              hipStream_t stream)
{
    const float* Hj   = (const float*)d_in[0];
    const float* Hi   = (const float*)d_in[1];
    const float* mask = (const float*)d_in[2];
    const float* Wpj  = (const float*)d_in[3];
    const float* Wpi  = (const float*)d_in[4];
    const float* W1   = (const float*)d_in[5];
    const float* b1   = (const float*)d_in[6];
    const float* W2   = (const float*)d_in[7];
    const float* Wv1  = (const float*)d_in[9];
    const float* bv1  = (const float*)d_in[10];
    const float* Wv2  = (const float*)d_in[11];
    const float* bv2  = (const float*)d_in[12];
    const float* alpha = (const float*)d_in[13];
    float* out = (float*)d_out;

    const int NR = NRR;                   // 2048
    char* p = (char*)d_ws;
    auto alloc = [&](size_t bytes) {
        char* r = p; p += (bytes + 255) & ~(size_t)255; return r;
    };
    unsigned* Zjp          = (unsigned*)alloc((size_t)NR*12*4);
    unsigned* Zip          = (unsigned*)alloc((size_t)NR*12*4);
    unsigned short* probsb = (unsigned short*)alloc((size_t)NR*SS*2);
    unsigned short* HiT    = (unsigned short*)alloc((size_t)BB*HH*SS*2);
    unsigned short* Wv1T   = (unsigned short*)alloc((size_t)VHIDD*VINN*2);
    unsigned short* Wv2T   = (unsigned short*)alloc((size_t)HH*VHIDD*2);
    unsigned short* msginb = (unsigned short*)alloc((size_t)NR*VINN*2);
    unsigned short* Y1b    = (unsigned short*)alloc((size_t)NR*VHIDD*2);
    float* Part            = (float*)alloc((size_t)4*NR*768*4);

    k_tconv<<<dim3(VHIDD/32, VINN/32, 1), 256, 0, stream>>>(Wv1, Wv1T, VINN, VHIDD);
    k_tconv<<<dim3(HH/32, VHIDD/32, 1), 256, 0, stream>>>(Wv2, Wv2T, VHIDD, HH);
    k_tconv<<<dim3(HH/32, SS/32, BB), 256, 0, stream>>>(Hi, HiT, SS, HH);
    k_zproj<<<2*NR/64, 256, 0, stream>>>(Hj, Hi, Wpj, Wpi, Zjp, Zip);
    k_attn<<<NR, 256, 0, stream>>>(Zjp, Zip, W1, b1, W2, mask, probsb);

    const int EPI_GRID = NR*192/256;      // 1536

    // ctx GEMM: M=2048 (batch via bt stride), N=768, K=1024, split 4
    k_mgemm_p<<<dim3(HH/128, NR/128, 4), 256, 0, stream>>>(
        probsb, HiT, Part, SS, HH*SS);
    k_epi<0><<<EPI_GRID, 256, 0, stream>>>(Part, nullptr, Hj, alpha, msginb);

    // MLP GEMM1: K=2304, split 4
    k_mgemm_p<<<dim3(VHIDD/128, NR/128, 4), 256, 0, stream>>>(
        msginb, Wv1T, Part, VINN, 0);
    k_epi<1><<<EPI_GRID, 256, 0, stream>>>(Part, bv1, nullptr, alpha, Y1b);

    // MLP GEMM2: K=768, split 4
    k_mgemm_p<<<dim3(HH/128, NR/128, 4), 256, 0, stream>>>(
        Y1b, Wv2T, Part, VHIDD, 0);
    k_epi<2><<<EPI_GRID, 256, 0, stream>>>(Part, bv2, nullptr, alpha, out);
}